// Round 9
// baseline (761.356 us; speedup 1.0000x reference)
//
#include <hip/hip_runtime.h>

#define B_   4
#define C_   192
#define E_   768
#define H0   64
#define H_   128
#define HW   (H_*H_)        // 16384
#define PLANE0 (H0*H0)      // 4096
#define NPIX (B_*HW)        // 65536
#define NOUT (B_*C_*HW)     // 12582912

// halo-padded pixel-major xm: [b][130][130][192] bf16, lives in d_out[0:NOUT]
#define XTW  130
#define XTPL (XTW*XTW)       // 16,900
#define XT_SHORTS (B_*XTPL*192)

// ws layout (bytes)
#define OFF_S    0u
#define OFF_FAC  262144u
#define OFF_MH   524288u
#define OFF_M1   3932160u    // u8 12,582,912
#define OFF_WEB3 16515072u   // 108 tiles x [384e][32c] bf16 = 2,654,208 (pair-swizzled)
#define OFF_WPB3 19169280u   // 12 chunks x [192co][64e] bf16 = 294,912 (XOR-closed)
#define OFF_GB   19464192u   // 192*192 bf16 = 73,728
// end 19,537,920

typedef __attribute__((ext_vector_type(8))) short bf16x8;
typedef __attribute__((ext_vector_type(4))) float f32x4;

__device__ __forceinline__ unsigned short f2bf(float f) {
    unsigned u = __float_as_uint(f);
    u += 0x7FFFu + ((u >> 16) & 1u);   // RNE
    return (unsigned short)(u >> 16);
}

__device__ __forceinline__ void gll16(const void* g, void* l) {
    __builtin_amdgcn_global_load_lds(
        (const __attribute__((address_space(1))) unsigned int*)g,
        (__attribute__((address_space(3))) unsigned int*)l, 16, 0, 0);
}

// ---------------- K0: zero halo ring of xmT ----------------
__global__ __launch_bounds__(256) void k_zhalo(short* __restrict__ xmT)
{
    int idx = blockIdx.x*256 + threadIdx.x;   // 4 * 516 * 24 = 49,536
    if (idx >= 49536) return;
    int g = idx % 24;
    int pp = (idx / 24) % 516;
    int b = idx / (24*516);
    int i, j;
    if (pp < 130)      { i = 0;   j = pp; }
    else if (pp < 260) { i = 129; j = pp - 130; }
    else { int q = pp - 260; i = 1 + (q >> 1); j = (q & 1) * 129; }
    *(bf16x8*)&xmT[((size_t)(b*XTPL + i*XTW + j))*192 + g*8] = (bf16x8)(short)0;
}

// ---------------- K1: fused partial IDWT + depthwise 3x3 partial conv ----------------
// One block per (b,c) plane; lo/hi -> pre -> cast all in LDS. No pre/mu globals.
__global__ __launch_bounds__(256) void k_idwtcast(
    const float* __restrict__ ll, const float* __restrict__ lh,
    const float* __restrict__ hl, const float* __restrict__ hh,
    const int* __restrict__ llm, const int* __restrict__ m1,
    const int* __restrict__ m2, const int* __restrict__ m3,
    const float* __restrict__ wc, const float* __restrict__ bcast,
    float* __restrict__ xm, unsigned char* __restrict__ m1out)
{
    const float G0c[7] = {-0.091271763114f,-0.057543526228f,0.591271763114f,1.115087052457f,
                          0.591271763114f,-0.057543526228f,-0.091271763114f};
    const float G1c[9] = {0.026748757411f,0.016864118443f,-0.078223266529f,-0.266864118443f,
                          0.602949018236f,-0.266864118443f,-0.078223266529f,0.016864118443f,
                          0.026748757411f};
    __shared__ __align__(16) char smem[148224];
    float* lo  = (float*)smem;                 // [128][64]  32,768
    float* hi  = (float*)(smem + 32768);       // [128][64]  32,768
    float* pre = (float*)(smem + 65536);       // [128][129] 66,048
    float* muf = (float*)(smem + 131584);      // [64][65]   16,640

    const int bc = blockIdx.x;
    const int base = bc * PLANE0;
    const int c = bc % C_;
    const int t = threadIdx.x;

    // phase A: vertical synthesis + mask union
    for (int idx = t; idx < H_*H0; idx += 256) {
        int o = idx >> 6, j = idx & 63;
        float alo = 0.f, ahi = 0.f;
        #pragma unroll
        for (int k = 0; k < 7; ++k) {
            int d = o + k - 3;
            if (d >= 0 && d <= 2*H0-2 && !(d & 1)) {
                int q = base + (d >> 1)*H0 + j;
                alo += G0c[k] * ll[q] * (float)llm[q];
                ahi += G0c[k] * hl[q] * (float)m2[q];
            }
        }
        #pragma unroll
        for (int k = 0; k < 9; ++k) {
            int d = o + k - 4;
            if (d >= 0 && d <= 2*H0-2 && !(d & 1)) {
                int q = base + (d >> 1)*H0 + j;
                alo += G1c[k] * lh[q] * (float)m1[q];
                ahi += G1c[k] * hh[q] * (float)m3[q];
            }
        }
        lo[idx] = alo; hi[idx] = ahi;
    }
    for (int idx = t; idx < PLANE0; idx += 256) {
        int q = base + idx;
        muf[(idx >> 6)*65 + (idx & 63)] = (llm[q] | m1[q] | m2[q] | m3[q]) ? 1.f : 0.f;
    }
    __syncthreads();
    // phase B: horizontal synthesis -> pre (LDS)
    for (int idx = t; idx < HW; idx += 256) {
        int o = idx >> 7, q = idx & 127;
        const float* lr = lo + o*H0;
        const float* hr = hi + o*H0;
        float v = 0.f;
        #pragma unroll
        for (int k = 0; k < 7; ++k) {
            int d = q + k - 3;
            if (d >= 0 && d <= 2*H0-2 && !(d & 1)) v += G0c[k] * lr[d >> 1];
        }
        #pragma unroll
        for (int k = 0; k < 9; ++k) {
            int d = q + k - 4;
            if (d >= 0 && d <= 2*H0-2 && !(d & 1)) v += G1c[k] * hr[d >> 1];
        }
        pre[o*129 + q] = v;
    }
    __syncthreads();
    // phase C: masked depthwise 3x3 + renorm -> xm, m1
    float w9[9];
    #pragma unroll
    for (int k = 0; k < 9; ++k) w9[k] = wc[c*9 + k];
    const float bcc = bcast[c];
    const size_t pb = (size_t)bc * HW;
    for (int idx = t; idx < 2048; idx += 256) {
        int row = idx >> 4, j8 = (idx & 15) * 8;
        float ox[8]; unsigned mo = 0, mo2 = 0;
        #pragma unroll
        for (int u = 0; u < 8; ++u) {
            int j = j8 + u;
            float o = 0.f, s = 0.f;
            #pragma unroll
            for (int di = 0; di < 3; ++di) {
                int gi = row + di - 1;
                #pragma unroll
                for (int dj = 0; dj < 3; ++dj) {
                    int gj = j + dj - 1;
                    if ((unsigned)gi < 128u && (unsigned)gj < 128u) {
                        float m0v = muf[(gi >> 1)*65 + (gj >> 1)];
                        s += m0v;
                        o += m0v * pre[gi*129 + gj] * w9[di*3 + dj];
                    }
                }
            }
            bool valid = s > 0.f;
            ox[u] = valid ? (o * (9.f / s) + bcc) : 0.f;
            unsigned bit = valid ? 1u : 0u;
            if (u < 4) mo |= bit << (8*u); else mo2 |= bit << (8*(u-4));
        }
        size_t oidx = pb + (size_t)row*128 + j8;
        f32x4 v0 = {ox[0], ox[1], ox[2], ox[3]};
        f32x4 v1 = {ox[4], ox[5], ox[6], ox[7]};
        *(f32x4*)&xm[oidx] = v0;
        *(f32x4*)&xm[oidx + 4] = v1;
        *(unsigned*)&m1out[oidx] = mo;
        *(unsigned*)&m1out[oidx + 4] = mo2;
    }
}

// ---------------- K3: channel-sum of mask1 ----------------
__global__ __launch_bounds__(128) void k_rowsum(const unsigned char* __restrict__ m1,
                                                float* __restrict__ S)
{
    int bi = blockIdx.x;
    int b = bi >> 7, i = bi & 127;
    int j = threadIdx.x;
    float s = 0.f;
    size_t base = (size_t)b*C_*HW + (size_t)i*H_ + j;
    for (int c = 0; c < C_; ++c) s += (float)m1[base + (size_t)c*HW];
    S[bi*H_ + j] = s;
}

// ---------------- K4: window-sum -> expand factor & mh ----------------
__global__ __launch_bounds__(256) void k_facm(const float* __restrict__ S,
                                              float* __restrict__ fac, float* __restrict__ mh)
{
    int px = blockIdx.x*256 + threadIdx.x;
    if (px >= NPIX) return;
    int j = px & 127, i = (px >> 7) & 127, b = px >> 14;
    float w3 = 0.f;
    #pragma unroll
    for (int di = -1; di <= 1; ++di) {
        int gi = i + di; if ((unsigned)gi >= (unsigned)H_) continue;
        #pragma unroll
        for (int dj = -1; dj <= 1; ++dj) {
            int gj = j + dj; if ((unsigned)gj >= (unsigned)H_) continue;
            w3 += S[(b*H_ + gi)*H_ + gj];
        }
    }
    bool v = w3 > 0.f;
    fac[px] = v ? 1728.f / w3 : 0.f;
    mh[px]  = v ? 1.f : 0.f;
}

// ---------------- K4b: weight convert + permute + pre-swizzle ----------------
// web3: 108 tiles (tile = p*54 + sc*9 + r) of [384e][32c] with ROW-PAIR swizzle:
//   linear granule G (0..1535): pair=G>>3, slot=G&7, x=slot^(pair&7),
//   e_loc=pair*2+(x>>2), c8=x&3 -> value we[(p*384+e_loc)*1728 + (sc*32+c8*8+j)*9 + r]
// wpb3: 12 chunks [192co][slot 8][8]: slot s holds e-group g=s^(co&7); e=chunk*64+g*8+j
// gb  : gamma bf16 [co][c]
__global__ __launch_bounds__(256) void k_wcvt(const float* __restrict__ we,
                                              const float* __restrict__ wp,
                                              const float* __restrict__ gamma,
                                              short* __restrict__ web3,
                                              short* __restrict__ wpb3,
                                              short* __restrict__ gb)
{
    int idx = blockIdx.x*256 + threadIdx.x;
    const int N1 = 108*12288;        // 1,327,104
    const int N2 = 12*C_*64;         // 147,456
    if (idx < N1) {
        int tile = idx / 12288, G2 = idx % 12288;
        int G = G2 >> 3, j = G2 & 7;
        int pair = G >> 3, slot = G & 7;
        int x = slot ^ (pair & 7);
        int e_loc = pair*2 + (x >> 2);
        int c8 = x & 3;
        int p = tile / 54, sc = (tile % 54) / 9, r = tile % 9;
        int e = p*384 + e_loc;
        int cg = sc*32 + c8*8 + j;
        web3[idx] = (short)f2bf(we[(size_t)e*1728 + cg*9 + r]);
    } else if (idx < N1 + N2) {
        int i2 = idx - N1;
        int chunk = i2 / 12288;
        int rem = i2 % 12288;
        int co = rem >> 6;
        int r3 = rem & 63;
        int s = r3 >> 3, j = r3 & 7;
        int g = s ^ (co & 7);
        wpb3[i2] = (short)f2bf(wp[(size_t)co*E_ + chunk*64 + (g << 3) + j]);
    } else {
        int i3 = idx - N1 - N2;
        if (i3 < C_*C_) gb[i3] = (short)f2bf(gamma[i3]);
    }
}

// ---------------- K4c: xm f32 [c][pix] -> xmT bf16 [b][130][130][192] (interior) ----------------
__global__ __launch_bounds__(256) void k_xmt(const float* __restrict__ xm,
                                             short* __restrict__ xmT)
{
    __shared__ float sm[64*65];
    const int gx = blockIdx.x;           // 3072 = 3 cb * 1024 pb
    const int cb = gx >> 10, pb = gx & 1023;
    const int c0 = cb*64, pix0 = pb*64;
    const int b = pix0 >> 14, pixb = pix0 & 16383;
    const int t = threadIdx.x;
    const int lane6 = t & 63, hi4 = t >> 6;
    #pragma unroll
    for (int it = 0; it < 16; ++it) {
        int r4 = it*4 + hi4;
        sm[r4*65 + lane6] = xm[((size_t)(b*C_ + c0 + r4))*HW + pixb + lane6];
    }
    __syncthreads();
    #pragma unroll
    for (int it = 0; it < 2; ++it) {
        int q = it*256 + t;
        int pp = q >> 3, c8 = q & 7;
        int p = pixb + pp;
        int i = p >> 7, j = p & 127;
        bf16x8 v;
        #pragma unroll
        for (int jj = 0; jj < 8; ++jj) v[jj] = (short)f2bf(sm[(c8*8+jj)*65 + pp]);
        *(bf16x8*)&xmT[((size_t)(b*XTPL + (i+1)*XTW + (j+1)))*192 + c0 + c8*8] = v;
    }
}

// ---------------- K5: MFMA fused MBConv, 128-px tile, 2 e-passes of 384 ----------------
// 512 blocks x 512 thr (8 waves, grid 2m x 4e). Per pass: 54 taps (6 sc of 32c x 9 taps),
// B triple-buffered [384e][32c] with row-pair swizzle; hB [128][384]; 6 wp chunks.
__global__ __launch_bounds__(512, 1) void k_mbconv(
    const short* __restrict__ xmT, const short* __restrict__ web3,
    const short* __restrict__ wpb3, const float* __restrict__ be,
    const float* __restrict__ bp, const float* __restrict__ bcast,
    const float* __restrict__ fac, const float* __restrict__ mh,
    const unsigned char* __restrict__ m1, float* __restrict__ xmy)
{
    __shared__ __align__(16) char smem[147456];
    // expand: apat @0 [90 pair][64] 11,520 | bB @11,520 [3][192 pair][64] 73,728 (ends 85,248)
    // proj:   wpB @0 [2][192co][64e] 49,152 | hB @49,152 [128px][384e] 98,304 (ends 147,456)
    // epi:    fbuf @0 [192][132] f32 101,376
    short* apat = (short*)smem;
    short* bB   = (short*)(smem + 11520);
    short* wpB  = (short*)smem;
    short* hB   = (short*)(smem + 49152);
    float* fbuf = (float*)smem;

    // XCD-aware swizzle: 512 blocks = 8 XCDs x 64 contiguous
    const int blk = (blockIdx.x & 7)*64 + (blockIdx.x >> 3);
    const int b = blk >> 7;                       // 4b x 16ti x 8tj
    const int ti = (blk >> 3) & 15, tj = blk & 7;
    const int i0 = ti*8, j0 = tj*16;              // tile = 8 rows x 16 cols
    const int t = threadIdx.x;
    const int w = t >> 6, l = t & 63;
    const int wm2 = w >> 2, we2 = w & 3;
    const int m0 = wm2 * 64;
    const int lo = l & 15, hi = l >> 4;

// A-patch [180 pos][32 c], row-pair swizzled. granule G: pair=G>>3, slot=G&7,
// x=slot^(pair&7), pos=pair*2+(x>>2), c8=x&3. 720 granules = 512 + 192 + 16(tail).
#define ISSUE_A(sc_) do {                                                       \
    const int c0_ = (sc_)*32;                                                   \
    for (int it_ = 0; it_ < 2; ++it_) {                                         \
        int q_ = it_*512 + t;                                                   \
        if (it_ == 1 && t >= 192) break;                                        \
        int pr_ = q_ >> 3, sl_ = q_ & 7;                                        \
        int x_ = sl_ ^ (pr_ & 7);                                               \
        int pos_ = pr_*2 + (x_ >> 2), c8_ = x_ & 3;                             \
        int rr_ = pos_/18, cc_ = pos_ - rr_*18;                                 \
        gll16(&xmT[((size_t)(b*XTPL + (i0+rr_)*XTW + (j0+cc_)))*192 + c0_       \
                   + c8_*8], &apat[q_*8]);                                      \
    }                                                                           \
    if (t < 16) {                                                               \
        int q_ = 704 + t;                                                       \
        int pr_ = q_ >> 3, sl_ = q_ & 7;                                        \
        int x_ = sl_ ^ (pr_ & 7);                                               \
        int pos_ = pr_*2 + (x_ >> 2), c8_ = x_ & 3;                             \
        int rr_ = pos_/18, cc_ = pos_ - rr_*18;                                 \
        bf16x8 v_ = *(const bf16x8*)&xmT[((size_t)(b*XTPL + (i0+rr_)*XTW        \
                   + (j0+cc_)))*192 + c0_ + c8_*8];                             \
        *(bf16x8*)&apat[q_*8] = v_;                                             \
    }                                                                           \
} while(0)

#define ISSUE_B(tileIdx_, bufIdx_) do {                                         \
    const size_t off_ = (size_t)(tileIdx_) * 12288;                             \
    short* dst_ = &bB[(bufIdx_) * 12288];                                       \
    for (int it_ = 0; it_ < 3; ++it_) {                                         \
        int q_ = it_*512 + t;                                                   \
        gll16(&web3[off_ + q_*8], &dst_[q_*8]);                                 \
    }                                                                           \
} while(0)

#define ISSUE_WP(chunkIdx_, bufIdx_) do {                                       \
    const size_t off_ = (size_t)(chunkIdx_) * 12288;                            \
    short* dst_ = &wpB[(bufIdx_) * 12288];                                      \
    for (int it_ = 0; it_ < 3; ++it_) {                                         \
        int q_ = it_*512 + t;                                                   \
        gll16(&wpb3[off_ + q_*8], &dst_[q_*8]);                                 \
    }                                                                           \
} while(0)

#define WAITBAR(N_) do {                                                        \
    asm volatile("s_waitcnt vmcnt(" #N_ ") lgkmcnt(0)" ::: "memory");           \
    __builtin_amdgcn_s_barrier();                                               \
    __builtin_amdgcn_sched_barrier(0);                                          \
} while(0)

#define LGKMBAR() do {                                                          \
    asm volatile("s_waitcnt lgkmcnt(0)" ::: "memory");                          \
    __builtin_amdgcn_s_barrier();                                               \
    __builtin_amdgcn_sched_barrier(0);                                          \
} while(0)

    float facr[4][4];
    #pragma unroll
    for (int af = 0; af < 4; ++af)
        #pragma unroll
        for (int reg = 0; reg < 4; ++reg) {
            int px = m0 + af*16 + hi*4 + reg;
            facr[af][reg] = fac[b*HW + (i0 + (px >> 4))*128 + j0 + (px & 15)];
        }
    int baseA[4];
    #pragma unroll
    for (int af = 0; af < 4; ++af) {
        int px = m0 + af*16 + lo;
        baseA[af] = (px >> 4)*18 + (px & 15);
    }

    // prologue
    ISSUE_A(0);
    ISSUE_B(0, 0);
    ISSUE_B(1, 1);

    #pragma unroll 1
    for (int p = 0; p < 2; ++p) {
        // ================= expand: 54 taps =================
        f32x4 acc[4][6];
        #pragma unroll
        for (int a = 0; a < 4; ++a)
            #pragma unroll
            for (int n = 0; n < 6; ++n) acc[a][n] = (f32x4){0.f,0.f,0.f,0.f};

        int sc = 0, r = 0, rj3 = 0, rv = 0, tm = 0;
        #pragma unroll 1
        for (int T = 0; T < 54; ++T) {
            const int d2 = (tm == 0) ? 2 : tm - 1;     // (T+2)%3
            if (r == 0 && sc > 0) {
                WAITBAR(3);                 // B[T] landed, old apat reads done
                ISSUE_A(sc);
                ISSUE_B(p*54 + T + 2, d2);  // boundaries at T<=45 -> T+2<=47 valid
                WAITBAR(3);                 // A landed, B[T+2] stays in flight
            } else if (T < 52) {
                WAITBAR(3);
                ISSUE_B(p*54 + T + 2, d2);
            } else if (T == 52) {
                WAITBAR(3);
            } else {
                WAITBAR(0);                 // T==53: last tile must land
            }
            const short* bcur = &bB[tm * 12288];
            bf16x8 a[4], bb[6];
            #pragma unroll
            for (int af = 0; af < 4; ++af) {
                int pos = baseA[af] + rv;
                a[af] = *(const bf16x8*)&apat[(pos>>1)*64
                        + ((((pos&1)*4 + hi) ^ ((pos>>1)&7))<<3)];
            }
            #pragma unroll
            for (int nf = 0; nf < 6; ++nf) {
                int e = we2*96 + nf*16 + lo;
                bb[nf] = *(const bf16x8*)&bcur[(e>>1)*64
                        + ((((e&1)*4 + hi) ^ ((e>>1)&7))<<3)];
            }
            __builtin_amdgcn_s_setprio(1);
            #pragma unroll
            for (int af = 0; af < 4; ++af)
                #pragma unroll
                for (int nf = 0; nf < 6; ++nf)
                    acc[af][nf] = __builtin_amdgcn_mfma_f32_16x16x32_bf16(
                        a[af], bb[nf], acc[af][nf], 0, 0, 0);
            __builtin_amdgcn_s_setprio(0);
            if (++rj3 == 3) { rj3 = 0; rv += 16; } else { ++rv; }
            if (++r == 9) { r = 0; ++sc; rv = 0; rj3 = 0; }
            tm = (tm == 2) ? 0 : tm + 1;
        }

        // ================= silu -> hB =================
        LGKMBAR();                         // tap-53 reads done; apat/bB dead
        ISSUE_WP(p*6, 0);
        #pragma unroll
        for (int nf = 0; nf < 6; ++nf) {
            int e_loc = we2*96 + nf*16 + lo;
            float bev = be[p*384 + e_loc];
            int ge = e_loc >> 3;
            #pragma unroll
            for (int af = 0; af < 4; ++af)
                #pragma unroll
                for (int reg = 0; reg < 4; ++reg) {
                    int px = m0 + af*16 + hi*4 + reg;
                    float fr = facr[af][reg];
                    float v = acc[af][nf][reg]*fr + bev;
                    float hv = (fr > 0.f) ? v / (1.f + __expf(-v)) : 0.f;
                    int ges = (ge & 56) | ((ge & 7) ^ (px & 7));
                    hB[px*384 + ges*8 + (e_loc & 7)] = (short)f2bf(hv);
                }
        }

        // ================= proj: 6 chunks of 64 e =================
        f32x4 accy[4][3];
        #pragma unroll
        for (int a = 0; a < 4; ++a)
            #pragma unroll
            for (int n = 0; n < 3; ++n) accy[a][n] = (f32x4){0.f,0.f,0.f,0.f};

        LGKMBAR();                         // silu hB writes visible to all
        #pragma unroll 1
        for (int ec = 0; ec < 6; ++ec) {
            if (ec > 0) LGKMBAR();         // prev-prev wpB buf reads done before restage
            if (ec < 5) {
                ISSUE_WP(p*6 + ec + 1, (ec + 1) & 1);
                asm volatile("s_waitcnt vmcnt(3) lgkmcnt(0)" ::: "memory");
            } else {
                asm volatile("s_waitcnt vmcnt(0) lgkmcnt(0)" ::: "memory");
            }
            __builtin_amdgcn_s_barrier();
            __builtin_amdgcn_sched_barrier(0);
            const short* wcur = &wpB[(ec & 1) * 12288];
            #pragma unroll
            for (int ks = 0; ks < 2; ++ks) {
                const int c8l = ks*4 + hi;
                bf16x8 a[4], bb[3];
                #pragma unroll
                for (int af = 0; af < 4; ++af) {
                    int px = m0 + af*16 + lo;
                    a[af] = *(const bf16x8*)&hB[px*384 + ((ec*8 + (c8l ^ (px&7)))<<3)];
                }
                #pragma unroll
                for (int nf = 0; nf < 3; ++nf) {
                    int co = we2*48 + nf*16 + lo;
                    bb[nf] = *(const bf16x8*)&wcur[co*64 + ((c8l ^ (co&7))<<3)];
                }
                __builtin_amdgcn_s_setprio(1);
                #pragma unroll
                for (int af = 0; af < 4; ++af)
                    #pragma unroll
                    for (int nf = 0; nf < 3; ++nf)
                        accy[af][nf] = __builtin_amdgcn_mfma_f32_16x16x32_bf16(
                            a[af], bb[nf], accy[af][nf], 0, 0, 0);
                __builtin_amdgcn_s_setprio(0);
            }
        }

        // ================= per-pass y accumulate (single fbuf phase) =================
        LGKMBAR();                         // proj reads done; hB/wpB dead
        #pragma unroll
        for (int af = 0; af < 4; ++af)
            #pragma unroll
            for (int nf = 0; nf < 3; ++nf) {
                int co = we2*48 + nf*16 + lo;
                int pxl = m0 + af*16 + hi*4;
                *(f32x4*)&fbuf[co*132 + pxl] = accy[af][nf];
            }
        __syncthreads();
        #pragma unroll 1
        for (int it = 0; it < 12; ++it) {
            int q = it*512 + t;              // 6144 = 192co x 32 px-quads
            int co = q >> 5, px4 = (q & 31) << 2;
            int pi = px4 >> 4, pj = px4 & 15;
            size_t gidx = ((size_t)(b*C_ + co))*HW + (size_t)(i0+pi)*128 + j0 + pj;
            f32x4 pv = *(f32x4*)&fbuf[co*132 + px4];
            f32x4 prev = *(const f32x4*)&xmy[gidx];
            f32x4 o;
            if (p == 0) {
                int pixg = b*HW + (i0+pi)*128 + j0 + pj;
                f32x4 mh4 = *(const f32x4*)&mh[pixg];
                unsigned mu4 = *(const unsigned*)&m1[gidx];
                float bpc = bp[co], bcc = bcast[co];
                #pragma unroll
                for (int k = 0; k < 4; ++k)
                    o[k] = pv[k] + bpc + prev[k] + bcc*(mh4[k] - (float)((mu4 >> (8*k)) & 255u));
            } else {
                #pragma unroll
                for (int k = 0; k < 4; ++k) o[k] = prev[k] + pv[k];
            }
            *(f32x4*)&xmy[gidx] = o;
        }
        __syncthreads();
        if (p == 0) { ISSUE_A(0); ISSUE_B(54, 0); ISSUE_B(55, 1); }
    }
#undef ISSUE_A
#undef ISSUE_B
#undef ISSUE_WP
#undef WAITBAR
#undef LGKMBAR
}

// ---------------- K6: MFMA GDN, 2x128 px tiles ----------------
__global__ __launch_bounds__(512, 2) void k_gdn(
    const short* __restrict__ gb, const float* __restrict__ beta,
    const float* __restrict__ mh, float* __restrict__ dout)
{
    __shared__ __align__(16) char smem[101376];
    short* aB = (short*)smem;               // [256][104] 53,248
    short* bG = (short*)(smem + 53248);     // [192][104] 39,936
    float* fbuf = (float*)smem;             // [192][132]
    const float* y = dout + NOUT;

    const int blk = blockIdx.x;             // 256 = 4b * 64 row-pairs
    const int b = blk >> 6;
    const int row0 = (blk & 63) * 2;
    const int t = threadIdx.x;
    const int w = t >> 6, l = t & 63;
    const int wm = w >> 1, we_ = w & 1;
    const int m0 = wm * 64;
    const int lo = l & 15, hi = l >> 4;

    f32x4 acc[4][6];
    #pragma unroll
    for (int a = 0; a < 4; ++a)
        #pragma unroll
        for (int n = 0; n < 6; ++n) acc[a][n] = (f32x4){0.f,0.f,0.f,0.f};

    #pragma unroll 1
    for (int ch = 0; ch < 2; ++ch) {
        __syncthreads();
        #pragma unroll 1
        for (int it = 0; it < 12; ++it) {
            int q = it*512 + t;                 // 6144 = 96c x 64 px-chunks
            int cL = q >> 6, px4 = (q & 63) << 2;
            int c = ch*96 + cL;
            int pi = px4 >> 7, pj = px4 & 127;
            f32x4 yv = *(const f32x4*)&y[((size_t)(b*C_ + c))*HW + (size_t)(row0+pi)*128 + pj];
            #pragma unroll
            for (int k = 0; k < 4; ++k)
                aB[(px4+k)*104 + cL] = (short)f2bf(yv[k]*yv[k]);
        }
        #pragma unroll 1
        for (int it = 0; it < 5; ++it) {
            int q = it*512 + t;
            if (q < 2304) {
                int co = q / 12, e8 = q - co*12;
                *(bf16x8*)&bG[co*104 + e8*8] = *(const bf16x8*)&gb[co*192 + ch*96 + e8*8];
            }
        }
        __syncthreads();
        #pragma unroll
        for (int ks = 0; ks < 3; ++ks) {
            const int koff = ks*32 + hi*8;
            bf16x8 a[4], bb[6];
            #pragma unroll
            for (int af = 0; af < 4; ++af)
                a[af] = *(const bf16x8*)&aB[(m0 + af*16 + lo)*104 + koff];
            #pragma unroll
            for (int nf = 0; nf < 6; ++nf)
                bb[nf] = *(const bf16x8*)&bG[(we_*96 + nf*16 + lo)*104 + koff];
            #pragma unroll
            for (int af = 0; af < 4; ++af)
                #pragma unroll
                for (int nf = 0; nf < 6; ++nf)
                    acc[af][nf] = __builtin_amdgcn_mfma_f32_16x16x32_bf16(
                        a[af], bb[nf], acc[af][nf], 0, 0, 0);
        }
    }

    #pragma unroll 1
    for (int ph = 0; ph < 2; ++ph) {
        __syncthreads();
        if ((wm >> 1) == ph) {
            #pragma unroll
            for (int af = 0; af < 4; ++af)
                #pragma unroll
                for (int nf = 0; nf < 6; ++nf) {
                    int co = we_*96 + nf*16 + lo;
                    int pxl = (wm&1)*64 + af*16 + hi*4;
                    *(f32x4*)&fbuf[co*132 + pxl] = acc[af][nf];
                }
        }
        __syncthreads();
        #pragma unroll 1
        for (int it = 0; it < 12; ++it) {
            int q = it*512 + t;
            int co = q >> 5, px4 = (q & 31) << 2;
            size_t gidx = ((size_t)(b*C_ + co))*HW + (size_t)(row0+ph)*128 + px4;
            int pixg = b*HW + (row0+ph)*128 + px4;
            f32x4 nv = *(f32x4*)&fbuf[co*132 + px4];
            f32x4 yv = *(const f32x4*)&y[gidx];
            f32x4 mh4 = *(const f32x4*)&mh[pixg];
            float bt = beta[co];
            f32x4 o;
            #pragma unroll
            for (int k = 0; k < 4; ++k)
                o[k] = (mh4[k] > 0.f) ? yv[k]*rsqrtf(bt + nv[k]) : 0.f;
            *(f32x4*)&dout[gidx] = o;
            *(f32x4*)&dout[(size_t)NOUT + gidx] = mh4;   // final mask (y read above)
        }
    }
}

extern "C" void kernel_launch(void* const* d_in, const int* in_sizes, int n_in,
                              void* d_out, int out_size, void* d_ws, size_t ws_size,
                              hipStream_t stream)
{
    const float* ll = (const float*)d_in[0];
    const float* b1 = (const float*)d_in[1];
    const float* b2 = (const float*)d_in[2];
    const float* b3 = (const float*)d_in[3];
    const int* llm = (const int*)d_in[4];
    const int* m1i = (const int*)d_in[5];
    const int* m2i = (const int*)d_in[6];
    const int* m3i = (const int*)d_in[7];
    const float* wc    = (const float*)d_in[8];
    const float* bcast = (const float*)d_in[9];
    const float* we    = (const float*)d_in[10];
    const float* be    = (const float*)d_in[11];
    const float* wp    = (const float*)d_in[12];
    const float* bp    = (const float*)d_in[13];
    const float* gamma = (const float*)d_in[14];
    const float* beta  = (const float*)d_in[15];

    char* ws = (char*)d_ws;
    float* S   = (float*)(ws + OFF_S);
    float* fac = (float*)(ws + OFF_FAC);
    float* mh  = (float*)(ws + OFF_MH);
    unsigned char* m1b = (unsigned char*)(ws + OFF_M1);
    short* web3 = (short*)(ws + OFF_WEB3);
    short* wpb3 = (short*)(ws + OFF_WPB3);
    short* gb   = (short*)(ws + OFF_GB);

    float* outF = (float*)d_out;
    float* xm  = outF + NOUT;       // [NOUT:2NOUT] xm -> y (in-place) -> final mask
    short* xmT = (short*)d_out;     // [0:NOUT] xmT halo -> final out

    k_wcvt<<<dim3(5904), dim3(256), 0, stream>>>(we, wp, gamma, web3, wpb3, gb);
    k_idwtcast<<<dim3(B_*C_), dim3(256), 0, stream>>>(ll, b1, b2, b3, llm, m1i, m2i, m3i,
                                                      wc, bcast, xm, m1b);
    k_zhalo<<<dim3(194), dim3(256), 0, stream>>>(xmT);
    k_xmt<<<dim3(3072), dim3(256), 0, stream>>>(xm, xmT);
    k_rowsum<<<dim3(B_*H_), dim3(128), 0, stream>>>(m1b, S);
    k_facm<<<dim3(NPIX/256), dim3(256), 0, stream>>>(S, fac, mh);
    k_mbconv<<<dim3(512), dim3(512), 0, stream>>>(xmT, web3, wpb3, be, bp, bcast, fac, mh, m1b, xm);
    k_gdn<<<dim3(256), dim3(512), 0, stream>>>(gb, beta, mh, outF);
}

// Round 10
// 635.464 us; speedup vs baseline: 1.1981x; 1.1981x over previous
//
#include <hip/hip_runtime.h>

#define B_   4
#define C_   192
#define E_   768
#define H0   64
#define H_   128
#define HW   (H_*H_)        // 16384
#define PLANE0 (H0*H0)      // 4096
#define NPIX (B_*HW)        // 65536
#define NOUT (B_*C_*HW)     // 12582912

// halo-padded pixel-major xm: [b][130][130][192] bf16, lives in d_out[0:NOUT]
#define XTW  130
#define XTPL (XTW*XTW)       // 16,900
#define XT_SHORTS (B_*XTPL*192)

// ws layout (bytes)
#define OFF_S    0u
#define OFF_FAC  262144u
#define OFF_MH   524288u
#define OFF_MU   786432u     // u8 3,145,728
#define OFF_M1   3932160u    // u8 12,582,912
#define OFF_WEB3 16515072u   // 108 tiles x [384e][32c] bf16 = 2,654,208 (pair-swizzled)
#define OFF_WPB3 19169280u   // 12 chunks x [192co][64e] bf16 = 294,912 (XOR-closed)
#define OFF_GB   19464192u   // 192*192 bf16 = 73,728
// end 19,537,920

// d_out (2*NOUT f32) timeline:
//   [0:NOUT]      pre (idwt..cast) -> xmT bf16 halo (zhalo..mbconv) -> final out (gdn)
//   [NOUT:2NOUT]  xm f32 (cast..mbconv RMW) -> y -> final mask

typedef __attribute__((ext_vector_type(8))) short bf16x8;
typedef __attribute__((ext_vector_type(4))) float f32x4;

__device__ __forceinline__ unsigned short f2bf(float f) {
    unsigned u = __float_as_uint(f);
    u += 0x7FFFu + ((u >> 16) & 1u);   // RNE
    return (unsigned short)(u >> 16);
}

__device__ __forceinline__ void gll16(const void* g, void* l) {
    __builtin_amdgcn_global_load_lds(
        (const __attribute__((address_space(1))) unsigned int*)g,
        (__attribute__((address_space(3))) unsigned int*)l, 16, 0, 0);
}

// ---------------- K0: zero halo ring of xmT ----------------
__global__ __launch_bounds__(256) void k_zhalo(short* __restrict__ xmT)
{
    int idx = blockIdx.x*256 + threadIdx.x;   // 4 * 516 * 24 = 49,536
    if (idx >= 49536) return;
    int g = idx % 24;
    int pp = (idx / 24) % 516;
    int b = idx / (24*516);
    int i, j;
    if (pp < 130)      { i = 0;   j = pp; }
    else if (pp < 260) { i = 129; j = pp - 130; }
    else { int q = pp - 260; i = 1 + (q >> 1); j = (q & 1) * 129; }
    *(bf16x8*)&xmT[((size_t)(b*XTPL + i*XTW + j))*192 + g*8] = (bf16x8)(short)0;
}

// ---------------- K1: partial IDWT + mask union ----------------
__global__ __launch_bounds__(256) void k_idwt(
    const float* __restrict__ ll, const float* __restrict__ lh,
    const float* __restrict__ hl, const float* __restrict__ hh,
    const int* __restrict__ llm, const int* __restrict__ m1,
    const int* __restrict__ m2, const int* __restrict__ m3,
    float* __restrict__ pre, unsigned char* __restrict__ mu)
{
    const float G0c[7] = {-0.091271763114f,-0.057543526228f,0.591271763114f,1.115087052457f,
                          0.591271763114f,-0.057543526228f,-0.091271763114f};
    const float G1c[9] = {0.026748757411f,0.016864118443f,-0.078223266529f,-0.266864118443f,
                          0.602949018236f,-0.266864118443f,-0.078223266529f,0.016864118443f,
                          0.026748757411f};
    __shared__ float lo[H_*H0];
    __shared__ float hi[H_*H0];
    const int bc = blockIdx.x;
    const int base = bc * PLANE0;
    const int t = threadIdx.x;
    for (int idx = t; idx < H_*H0; idx += 256) {
        int o = idx >> 6, j = idx & 63;
        float alo = 0.f, ahi = 0.f;
        #pragma unroll
        for (int k = 0; k < 7; ++k) {
            int d = o + k - 3;
            if (d >= 0 && d <= 2*H0-2 && !(d & 1)) {
                int q = base + (d >> 1)*H0 + j;
                alo += G0c[k] * ll[q] * (float)llm[q];
                ahi += G0c[k] * hl[q] * (float)m2[q];
            }
        }
        #pragma unroll
        for (int k = 0; k < 9; ++k) {
            int d = o + k - 4;
            if (d >= 0 && d <= 2*H0-2 && !(d & 1)) {
                int q = base + (d >> 1)*H0 + j;
                alo += G1c[k] * lh[q] * (float)m1[q];
                ahi += G1c[k] * hh[q] * (float)m3[q];
            }
        }
        lo[idx] = alo; hi[idx] = ahi;
    }
    for (int idx = t; idx < PLANE0; idx += 256) {
        int q = base + idx;
        mu[q] = (unsigned char)((llm[q] | m1[q] | m2[q] | m3[q]) ? 1 : 0);
    }
    __syncthreads();
    const size_t ob = (size_t)bc * HW;
    for (int idx = t; idx < HW; idx += 256) {
        int o = idx >> 7, q = idx & 127;
        const float* lr = lo + o*H0;
        const float* hr = hi + o*H0;
        float v = 0.f;
        #pragma unroll
        for (int k = 0; k < 7; ++k) {
            int d = q + k - 3;
            if (d >= 0 && d <= 2*H0-2 && !(d & 1)) v += G0c[k] * lr[d >> 1];
        }
        #pragma unroll
        for (int k = 0; k < 9; ++k) {
            int d = q + k - 4;
            if (d >= 0 && d <= 2*H0-2 && !(d & 1)) v += G1c[k] * hr[d >> 1];
        }
        pre[ob + idx] = v;
    }
}

// ---------------- K2: depthwise 3x3 partial conv (cast), LDS-tiled ----------------
__global__ __launch_bounds__(256) void k_cast(
    const float* __restrict__ pre, const unsigned char* __restrict__ mu,
    const float* __restrict__ wc, const float* __restrict__ bcast,
    float* __restrict__ xm, unsigned char* __restrict__ m1out)
{
    __shared__ float sp[18*131];
    __shared__ float smv[10*66];
    const int blk = blockIdx.x;          // 6144 = 768 bc x 8 row-tiles
    const int bc = blk >> 3;
    const int i0 = (blk & 7) * 16;
    const int c = bc % C_;
    const int t = threadIdx.x;
    const size_t pb = (size_t)bc * HW;
    const size_t mb = (size_t)bc * PLANE0;
    for (int q = t; q < 2340; q += 256) {
        int rr = q / 130, cc = q - rr*130;
        int gi = i0 + rr - 1, gj = cc - 1;
        float v = 0.f;
        if ((unsigned)gi < 128u && (unsigned)gj < 128u) v = pre[pb + gi*128 + gj];
        sp[rr*131 + cc] = v;
    }
    for (int q = t; q < 660; q += 256) {
        int rr = q / 66, cc = q - rr*66;
        int mi = (i0 >> 1) + rr - 1, mj = cc - 1;
        float v = 0.f;
        if ((unsigned)mi < 64u && (unsigned)mj < 64u) v = (float)mu[mb + mi*64 + mj];
        smv[rr*66 + cc] = v;
    }
    __syncthreads();
    float w9[9];
    #pragma unroll
    for (int k = 0; k < 9; ++k) w9[k] = wc[c*9 + k];
    const float bcc = bcast[c];
    const int rr = t >> 4, c8 = (t & 15) * 8;
    float ox[8]; unsigned mo = 0, mo2 = 0;
    #pragma unroll
    for (int u = 0; u < 8; ++u) {
        int j = c8 + u;
        float o = 0.f, s = 0.f;
        #pragma unroll
        for (int di = 0; di < 3; ++di) {
            int gi = i0 + rr + di - 1;
            int mrow = (gi >> 1) - (i0 >> 1) + 1;
            #pragma unroll
            for (int dj = 0; dj < 3; ++dj) {
                int gj = j + dj - 1;
                float m0v = smv[mrow*66 + (gj >> 1) + 1];
                s += m0v;
                o += m0v * sp[(rr+di)*131 + j + dj] * w9[di*3 + dj];
            }
        }
        bool valid = s > 0.f;
        ox[u] = valid ? (o * (9.f / s) + bcc) : 0.f;
        unsigned bit = valid ? 1u : 0u;
        if (u < 4) mo |= bit << (8*u); else mo2 |= bit << (8*(u-4));
    }
    size_t oidx = pb + (size_t)(i0 + rr)*128 + c8;
    f32x4 v0 = {ox[0], ox[1], ox[2], ox[3]};
    f32x4 v1 = {ox[4], ox[5], ox[6], ox[7]};
    *(f32x4*)&xm[oidx] = v0;
    *(f32x4*)&xm[oidx + 4] = v1;
    *(unsigned*)&m1out[oidx] = mo;
    *(unsigned*)&m1out[oidx + 4] = mo2;
}

// ---------------- K3: channel-sum of mask1 ----------------
__global__ __launch_bounds__(128) void k_rowsum(const unsigned char* __restrict__ m1,
                                                float* __restrict__ S)
{
    int bi = blockIdx.x;
    int b = bi >> 7, i = bi & 127;
    int j = threadIdx.x;
    float s = 0.f;
    size_t base = (size_t)b*C_*HW + (size_t)i*H_ + j;
    for (int c = 0; c < C_; ++c) s += (float)m1[base + (size_t)c*HW];
    S[bi*H_ + j] = s;
}

// ---------------- K4: window-sum -> expand factor & mh ----------------
__global__ __launch_bounds__(256) void k_facm(const float* __restrict__ S,
                                              float* __restrict__ fac, float* __restrict__ mh)
{
    int px = blockIdx.x*256 + threadIdx.x;
    if (px >= NPIX) return;
    int j = px & 127, i = (px >> 7) & 127, b = px >> 14;
    float w3 = 0.f;
    #pragma unroll
    for (int di = -1; di <= 1; ++di) {
        int gi = i + di; if ((unsigned)gi >= (unsigned)H_) continue;
        #pragma unroll
        for (int dj = -1; dj <= 1; ++dj) {
            int gj = j + dj; if ((unsigned)gj >= (unsigned)H_) continue;
            w3 += S[(b*H_ + gi)*H_ + gj];
        }
    }
    bool v = w3 > 0.f;
    fac[px] = v ? 1728.f / w3 : 0.f;
    mh[px]  = v ? 1.f : 0.f;
}

// ---------------- K4b: weight convert + permute + pre-swizzle ----------------
// web3: 108 tiles (tile = p*54 + sc*9 + r) of [384e][32c] with ROW-PAIR swizzle:
//   linear granule G (0..1535): pair=G>>3, slot=G&7, x=slot^(pair&7),
//   e_loc=pair*2+(x>>2), c8=x&3 -> value we[(p*384+e_loc)*1728 + (sc*32+c8*8+j)*9 + r]
// wpb3: 12 chunks [192co][slot 8][8]: slot s holds e-group g=s^(co&7); e=chunk*64+g*8+j
// gb  : gamma bf16 [co][c]
__global__ __launch_bounds__(256) void k_wcvt(const float* __restrict__ we,
                                              const float* __restrict__ wp,
                                              const float* __restrict__ gamma,
                                              short* __restrict__ web3,
                                              short* __restrict__ wpb3,
                                              short* __restrict__ gb)
{
    int idx = blockIdx.x*256 + threadIdx.x;
    const int N1 = 108*12288;        // 1,327,104
    const int N2 = 12*C_*64;         // 147,456
    if (idx < N1) {
        int tile = idx / 12288, G2 = idx % 12288;
        int G = G2 >> 3, j = G2 & 7;
        int pair = G >> 3, slot = G & 7;
        int x = slot ^ (pair & 7);
        int e_loc = pair*2 + (x >> 2);
        int c8 = x & 3;
        int p = tile / 54, sc = (tile % 54) / 9, r = tile % 9;
        int e = p*384 + e_loc;
        int cg = sc*32 + c8*8 + j;
        web3[idx] = (short)f2bf(we[(size_t)e*1728 + cg*9 + r]);
    } else if (idx < N1 + N2) {
        int i2 = idx - N1;
        int chunk = i2 / 12288;
        int rem = i2 % 12288;
        int co = rem >> 6;
        int r3 = rem & 63;
        int s = r3 >> 3, j = r3 & 7;
        int g = s ^ (co & 7);
        wpb3[i2] = (short)f2bf(wp[(size_t)co*E_ + chunk*64 + (g << 3) + j]);
    } else {
        int i3 = idx - N1 - N2;
        if (i3 < C_*C_) gb[i3] = (short)f2bf(gamma[i3]);
    }
}

// ---------------- K4c: xm f32 [c][pix] -> xmT bf16 [b][130][130][192] (interior) ----------------
__global__ __launch_bounds__(256) void k_xmt(const float* __restrict__ xm,
                                             short* __restrict__ xmT)
{
    __shared__ float sm[64*65];
    const int gx = blockIdx.x;           // 3072 = 3 cb * 1024 pb
    const int cb = gx >> 10, pb = gx & 1023;
    const int c0 = cb*64, pix0 = pb*64;
    const int b = pix0 >> 14, pixb = pix0 & 16383;
    const int t = threadIdx.x;
    const int lane6 = t & 63, hi4 = t >> 6;
    #pragma unroll
    for (int it = 0; it < 16; ++it) {
        int r4 = it*4 + hi4;
        sm[r4*65 + lane6] = xm[((size_t)(b*C_ + c0 + r4))*HW + pixb + lane6];
    }
    __syncthreads();
    #pragma unroll
    for (int it = 0; it < 2; ++it) {
        int q = it*256 + t;
        int pp = q >> 3, c8 = q & 7;
        int p = pixb + pp;
        int i = p >> 7, j = p & 127;
        bf16x8 v;
        #pragma unroll
        for (int jj = 0; jj < 8; ++jj) v[jj] = (short)f2bf(sm[(c8*8+jj)*65 + pp]);
        *(bf16x8*)&xmT[((size_t)(b*XTPL + (i+1)*XTW + (j+1)))*192 + c0 + c8*8] = v;
    }
}

// ---------------- K5: MFMA fused MBConv, 128-px tile, 2 e-passes of 384 ----------------
// 512 blocks x 512 thr (8 waves, grid 2m x 4e). Per pass: 54 taps (6 sc of 32c x 9 taps),
// B triple-buffered [384e][32c] with row-pair swizzle; hB [128][384]; 6 wp chunks.
__global__ __launch_bounds__(512, 1) void k_mbconv(
    const short* __restrict__ xmT, const short* __restrict__ web3,
    const short* __restrict__ wpb3, const float* __restrict__ be,
    const float* __restrict__ bp, const float* __restrict__ bcast,
    const float* __restrict__ fac, const float* __restrict__ mh,
    const unsigned char* __restrict__ m1, float* __restrict__ xmy)
{
    __shared__ __align__(16) char smem[147456];
    // expand: apat @0 [90 pair][64] 11,520 | bB @11,520 [3][192 pair][64] 73,728 (ends 85,248)
    // proj:   wpB @0 [2][192co][64e] 49,152 | hB @49,152 [128px][384e] 98,304 (ends 147,456)
    // epi:    fbuf @0 [192][132] f32 101,376
    short* apat = (short*)smem;
    short* bB   = (short*)(smem + 11520);
    short* wpB  = (short*)smem;
    short* hB   = (short*)(smem + 49152);
    float* fbuf = (float*)smem;

    // XCD-aware swizzle: 512 blocks = 8 XCDs x 64 contiguous
    const int blk = (blockIdx.x & 7)*64 + (blockIdx.x >> 3);
    const int b = blk >> 7;                       // 4b x 16ti x 8tj
    const int ti = (blk >> 3) & 15, tj = blk & 7;
    const int i0 = ti*8, j0 = tj*16;              // tile = 8 rows x 16 cols
    const int t = threadIdx.x;
    const int w = t >> 6, l = t & 63;
    const int wm2 = w >> 2, we2 = w & 3;
    const int m0 = wm2 * 64;
    const int lo = l & 15, hi = l >> 4;

// A-patch [180 pos][32 c], row-pair swizzled. granule G: pair=G>>3, slot=G&7,
// x=slot^(pair&7), pos=pair*2+(x>>2), c8=x&3. 720 granules = 512 + 192 + 16(tail).
#define ISSUE_A(sc_) do {                                                       \
    const int c0_ = (sc_)*32;                                                   \
    for (int it_ = 0; it_ < 2; ++it_) {                                         \
        int q_ = it_*512 + t;                                                   \
        if (it_ == 1 && t >= 192) break;                                        \
        int pr_ = q_ >> 3, sl_ = q_ & 7;                                        \
        int x_ = sl_ ^ (pr_ & 7);                                               \
        int pos_ = pr_*2 + (x_ >> 2), c8_ = x_ & 3;                             \
        int rr_ = pos_/18, cc_ = pos_ - rr_*18;                                 \
        gll16(&xmT[((size_t)(b*XTPL + (i0+rr_)*XTW + (j0+cc_)))*192 + c0_       \
                   + c8_*8], &apat[q_*8]);                                      \
    }                                                                           \
    if (t < 16) {                                                               \
        int q_ = 704 + t;                                                       \
        int pr_ = q_ >> 3, sl_ = q_ & 7;                                        \
        int x_ = sl_ ^ (pr_ & 7);                                               \
        int pos_ = pr_*2 + (x_ >> 2), c8_ = x_ & 3;                             \
        int rr_ = pos_/18, cc_ = pos_ - rr_*18;                                 \
        bf16x8 v_ = *(const bf16x8*)&xmT[((size_t)(b*XTPL + (i0+rr_)*XTW        \
                   + (j0+cc_)))*192 + c0_ + c8_*8];                             \
        *(bf16x8*)&apat[q_*8] = v_;                                             \
    }                                                                           \
} while(0)

#define ISSUE_B(tileIdx_, bufIdx_) do {                                         \
    const size_t off_ = (size_t)(tileIdx_) * 12288;                             \
    short* dst_ = &bB[(bufIdx_) * 12288];                                       \
    for (int it_ = 0; it_ < 3; ++it_) {                                         \
        int q_ = it_*512 + t;                                                   \
        gll16(&web3[off_ + q_*8], &dst_[q_*8]);                                 \
    }                                                                           \
} while(0)

#define ISSUE_WP(chunkIdx_, bufIdx_) do {                                       \
    const size_t off_ = (size_t)(chunkIdx_) * 12288;                            \
    short* dst_ = &wpB[(bufIdx_) * 12288];                                      \
    for (int it_ = 0; it_ < 3; ++it_) {                                         \
        int q_ = it_*512 + t;                                                   \
        gll16(&wpb3[off_ + q_*8], &dst_[q_*8]);                                 \
    }                                                                           \
} while(0)

#define WAITBAR(N_) do {                                                        \
    asm volatile("s_waitcnt vmcnt(" #N_ ") lgkmcnt(0)" ::: "memory");           \
    __builtin_amdgcn_s_barrier();                                               \
    __builtin_amdgcn_sched_barrier(0);                                          \
} while(0)

#define LGKMBAR() do {                                                          \
    asm volatile("s_waitcnt lgkmcnt(0)" ::: "memory");                          \
    __builtin_amdgcn_s_barrier();                                               \
    __builtin_amdgcn_sched_barrier(0);                                          \
} while(0)

    float facr[4][4];
    #pragma unroll
    for (int af = 0; af < 4; ++af)
        #pragma unroll
        for (int reg = 0; reg < 4; ++reg) {
            int px = m0 + af*16 + hi*4 + reg;
            facr[af][reg] = fac[b*HW + (i0 + (px >> 4))*128 + j0 + (px & 15)];
        }
    int baseA[4];
    #pragma unroll
    for (int af = 0; af < 4; ++af) {
        int px = m0 + af*16 + lo;
        baseA[af] = (px >> 4)*18 + (px & 15);
    }

    // prologue
    ISSUE_A(0);
    ISSUE_B(0, 0);
    ISSUE_B(1, 1);

    #pragma unroll 1
    for (int p = 0; p < 2; ++p) {
        // ================= expand: 54 taps =================
        f32x4 acc[4][6];
        #pragma unroll
        for (int a = 0; a < 4; ++a)
            #pragma unroll
            for (int n = 0; n < 6; ++n) acc[a][n] = (f32x4){0.f,0.f,0.f,0.f};

        int sc = 0, r = 0, rj3 = 0, rv = 0, tm = 0;
        #pragma unroll 1
        for (int T = 0; T < 54; ++T) {
            const int d2 = (tm == 0) ? 2 : tm - 1;     // (T+2)%3
            if (r == 0 && sc > 0) {
                WAITBAR(3);                 // B[T] landed, old apat reads done
                ISSUE_A(sc);
                ISSUE_B(p*54 + T + 2, d2);
                WAITBAR(3);                 // A landed, B[T+2] stays in flight
            } else if (T < 52) {
                WAITBAR(3);
                ISSUE_B(p*54 + T + 2, d2);
            } else if (T == 52) {
                WAITBAR(3);
            } else {
                WAITBAR(0);                 // T==53: last tile must land
            }
            const short* bcur = &bB[tm * 12288];
            bf16x8 a[4], bb[6];
            #pragma unroll
            for (int af = 0; af < 4; ++af) {
                int pos = baseA[af] + rv;
                a[af] = *(const bf16x8*)&apat[(pos>>1)*64
                        + ((((pos&1)*4 + hi) ^ ((pos>>1)&7))<<3)];
            }
            #pragma unroll
            for (int nf = 0; nf < 6; ++nf) {
                int e = we2*96 + nf*16 + lo;
                bb[nf] = *(const bf16x8*)&bcur[(e>>1)*64
                        + ((((e&1)*4 + hi) ^ ((e>>1)&7))<<3)];
            }
            __builtin_amdgcn_s_setprio(1);
            #pragma unroll
            for (int af = 0; af < 4; ++af)
                #pragma unroll
                for (int nf = 0; nf < 6; ++nf)
                    acc[af][nf] = __builtin_amdgcn_mfma_f32_16x16x32_bf16(
                        a[af], bb[nf], acc[af][nf], 0, 0, 0);
            __builtin_amdgcn_s_setprio(0);
            if (++rj3 == 3) { rj3 = 0; rv += 16; } else { ++rv; }
            if (++r == 9) { r = 0; ++sc; rv = 0; rj3 = 0; }
            tm = (tm == 2) ? 0 : tm + 1;
        }

        // ================= silu -> hB =================
        LGKMBAR();                         // tap-53 reads done; apat/bB dead
        ISSUE_WP(p*6, 0);
        #pragma unroll
        for (int nf = 0; nf < 6; ++nf) {
            int e_loc = we2*96 + nf*16 + lo;
            float bev = be[p*384 + e_loc];
            int ge = e_loc >> 3;
            #pragma unroll
            for (int af = 0; af < 4; ++af)
                #pragma unroll
                for (int reg = 0; reg < 4; ++reg) {
                    int px = m0 + af*16 + hi*4 + reg;
                    float fr = facr[af][reg];
                    float v = acc[af][nf][reg]*fr + bev;
                    float hv = (fr > 0.f) ? v / (1.f + __expf(-v)) : 0.f;
                    int ges = (ge & 56) | ((ge & 7) ^ (px & 7));
                    hB[px*384 + ges*8 + (e_loc & 7)] = (short)f2bf(hv);
                }
        }

        // ================= proj: 6 chunks of 64 e =================
        f32x4 accy[4][3];
        #pragma unroll
        for (int a = 0; a < 4; ++a)
            #pragma unroll
            for (int n = 0; n < 3; ++n) accy[a][n] = (f32x4){0.f,0.f,0.f,0.f};

        LGKMBAR();                         // silu hB writes visible to all
        #pragma unroll 1
        for (int ec = 0; ec < 6; ++ec) {
            if (ec > 0) LGKMBAR();         // prev-prev wpB buf reads done before restage
            if (ec < 5) {
                ISSUE_WP(p*6 + ec + 1, (ec + 1) & 1);
                asm volatile("s_waitcnt vmcnt(3) lgkmcnt(0)" ::: "memory");
            } else {
                asm volatile("s_waitcnt vmcnt(0) lgkmcnt(0)" ::: "memory");
            }
            __builtin_amdgcn_s_barrier();
            __builtin_amdgcn_sched_barrier(0);
            const short* wcur = &wpB[(ec & 1) * 12288];
            #pragma unroll
            for (int ks = 0; ks < 2; ++ks) {
                const int c8l = ks*4 + hi;
                bf16x8 a[4], bb[3];
                #pragma unroll
                for (int af = 0; af < 4; ++af) {
                    int px = m0 + af*16 + lo;
                    a[af] = *(const bf16x8*)&hB[px*384 + ((ec*8 + (c8l ^ (px&7)))<<3)];
                }
                #pragma unroll
                for (int nf = 0; nf < 3; ++nf) {
                    int co = we2*48 + nf*16 + lo;
                    bb[nf] = *(const bf16x8*)&wcur[co*64 + ((c8l ^ (co&7))<<3)];
                }
                __builtin_amdgcn_s_setprio(1);
                #pragma unroll
                for (int af = 0; af < 4; ++af)
                    #pragma unroll
                    for (int nf = 0; nf < 3; ++nf)
                        accy[af][nf] = __builtin_amdgcn_mfma_f32_16x16x32_bf16(
                            a[af], bb[nf], accy[af][nf], 0, 0, 0);
                __builtin_amdgcn_s_setprio(0);
            }
        }

        // ================= per-pass y accumulate (single fbuf phase) =================
        LGKMBAR();                         // proj reads done; hB/wpB dead
        #pragma unroll
        for (int af = 0; af < 4; ++af)
            #pragma unroll
            for (int nf = 0; nf < 3; ++nf) {
                int co = we2*48 + nf*16 + lo;
                int pxl = m0 + af*16 + hi*4;
                *(f32x4*)&fbuf[co*132 + pxl] = accy[af][nf];
            }
        __syncthreads();
        #pragma unroll 1
        for (int it = 0; it < 12; ++it) {
            int q = it*512 + t;              // 6144 = 192co x 32 px-quads
            int co = q >> 5, px4 = (q & 31) << 2;
            int pi = px4 >> 4, pj = px4 & 15;
            size_t gidx = ((size_t)(b*C_ + co))*HW + (size_t)(i0+pi)*128 + j0 + pj;
            f32x4 pv = *(f32x4*)&fbuf[co*132 + px4];
            f32x4 prev = *(const f32x4*)&xmy[gidx];
            f32x4 o;
            if (p == 0) {
                int pixg = b*HW + (i0+pi)*128 + j0 + pj;
                f32x4 mh4 = *(const f32x4*)&mh[pixg];
                unsigned mu4 = *(const unsigned*)&m1[gidx];
                float bpc = bp[co], bcc = bcast[co];
                #pragma unroll
                for (int k = 0; k < 4; ++k)
                    o[k] = pv[k] + bpc + prev[k] + bcc*(mh4[k] - (float)((mu4 >> (8*k)) & 255u));
            } else {
                #pragma unroll
                for (int k = 0; k < 4; ++k) o[k] = prev[k] + pv[k];
            }
            *(f32x4*)&xmy[gidx] = o;
        }
        __syncthreads();
        if (p == 0) { ISSUE_A(0); ISSUE_B(54, 0); ISSUE_B(55, 1); }
    }
#undef ISSUE_A
#undef ISSUE_B
#undef ISSUE_WP
#undef WAITBAR
#undef LGKMBAR
}

// ---------------- K6: MFMA GDN, 2x128 px tiles ----------------
__global__ __launch_bounds__(512, 2) void k_gdn(
    const short* __restrict__ gb, const float* __restrict__ beta,
    const float* __restrict__ mh, float* __restrict__ dout)
{
    __shared__ __align__(16) char smem[101376];
    short* aB = (short*)smem;               // [256][104] 53,248
    short* bG = (short*)(smem + 53248);     // [192][104] 39,936
    float* fbuf = (float*)smem;             // [192][132]
    const float* y = dout + NOUT;

    const int blk = blockIdx.x;             // 256 = 4b * 64 row-pairs
    const int b = blk >> 6;
    const int row0 = (blk & 63) * 2;
    const int t = threadIdx.x;
    const int w = t >> 6, l = t & 63;
    const int wm = w >> 1, we_ = w & 1;
    const int m0 = wm * 64;
    const int lo = l & 15, hi = l >> 4;

    f32x4 acc[4][6];
    #pragma unroll
    for (int a = 0; a < 4; ++a)
        #pragma unroll
        for (int n = 0; n < 6; ++n) acc[a][n] = (f32x4){0.f,0.f,0.f,0.f};

    #pragma unroll 1
    for (int ch = 0; ch < 2; ++ch) {
        __syncthreads();
        #pragma unroll 1
        for (int it = 0; it < 12; ++it) {
            int q = it*512 + t;                 // 6144 = 96c x 64 px-chunks
            int cL = q >> 6, px4 = (q & 63) << 2;
            int c = ch*96 + cL;
            int pi = px4 >> 7, pj = px4 & 127;
            f32x4 yv = *(const f32x4*)&y[((size_t)(b*C_ + c))*HW + (size_t)(row0+pi)*128 + pj];
            #pragma unroll
            for (int k = 0; k < 4; ++k)
                aB[(px4+k)*104 + cL] = (short)f2bf(yv[k]*yv[k]);
        }
        #pragma unroll 1
        for (int it = 0; it < 5; ++it) {
            int q = it*512 + t;
            if (q < 2304) {
                int co = q / 12, e8 = q - co*12;
                *(bf16x8*)&bG[co*104 + e8*8] = *(const bf16x8*)&gb[co*192 + ch*96 + e8*8];
            }
        }
        __syncthreads();
        #pragma unroll
        for (int ks = 0; ks < 3; ++ks) {
            const int koff = ks*32 + hi*8;
            bf16x8 a[4], bb[6];
            #pragma unroll
            for (int af = 0; af < 4; ++af)
                a[af] = *(const bf16x8*)&aB[(m0 + af*16 + lo)*104 + koff];
            #pragma unroll
            for (int nf = 0; nf < 6; ++nf)
                bb[nf] = *(const bf16x8*)&bG[(we_*96 + nf*16 + lo)*104 + koff];
            #pragma unroll
            for (int af = 0; af < 4; ++af)
                #pragma unroll
                for (int nf = 0; nf < 6; ++nf)
                    acc[af][nf] = __builtin_amdgcn_mfma_f32_16x16x32_bf16(
                        a[af], bb[nf], acc[af][nf], 0, 0, 0);
        }
    }

    #pragma unroll 1
    for (int ph = 0; ph < 2; ++ph) {
        __syncthreads();
        if ((wm >> 1) == ph) {
            #pragma unroll
            for (int af = 0; af < 4; ++af)
                #pragma unroll
                for (int nf = 0; nf < 6; ++nf) {
                    int co = we_*96 + nf*16 + lo;
                    int pxl = (wm&1)*64 + af*16 + hi*4;
                    *(f32x4*)&fbuf[co*132 + pxl] = acc[af][nf];
                }
        }
        __syncthreads();
        #pragma unroll 1
        for (int it = 0; it < 12; ++it) {
            int q = it*512 + t;
            int co = q >> 5, px4 = (q & 31) << 2;
            size_t gidx = ((size_t)(b*C_ + co))*HW + (size_t)(row0+ph)*128 + px4;
            int pixg = b*HW + (row0+ph)*128 + px4;
            f32x4 nv = *(f32x4*)&fbuf[co*132 + px4];
            f32x4 yv = *(const f32x4*)&y[gidx];
            f32x4 mh4 = *(const f32x4*)&mh[pixg];
            float bt = beta[co];
            f32x4 o;
            #pragma unroll
            for (int k = 0; k < 4; ++k)
                o[k] = (mh4[k] > 0.f) ? yv[k]*rsqrtf(bt + nv[k]) : 0.f;
            *(f32x4*)&dout[gidx] = o;
            *(f32x4*)&dout[(size_t)NOUT + gidx] = mh4;   // final mask (y read above)
        }
    }
}

extern "C" void kernel_launch(void* const* d_in, const int* in_sizes, int n_in,
                              void* d_out, int out_size, void* d_ws, size_t ws_size,
                              hipStream_t stream)
{
    const float* ll = (const float*)d_in[0];
    const float* b1 = (const float*)d_in[1];
    const float* b2 = (const float*)d_in[2];
    const float* b3 = (const float*)d_in[3];
    const int* llm = (const int*)d_in[4];
    const int* m1i = (const int*)d_in[5];
    const int* m2i = (const int*)d_in[6];
    const int* m3i = (const int*)d_in[7];
    const float* wc    = (const float*)d_in[8];
    const float* bcast = (const float*)d_in[9];
    const float* we    = (const float*)d_in[10];
    const float* be    = (const float*)d_in[11];
    const float* wp    = (const float*)d_in[12];
    const float* bp    = (const float*)d_in[13];
    const float* gamma = (const float*)d_in[14];
    const float* beta  = (const float*)d_in[15];

    char* ws = (char*)d_ws;
    float* S   = (float*)(ws + OFF_S);
    float* fac = (float*)(ws + OFF_FAC);
    float* mh  = (float*)(ws + OFF_MH);
    unsigned char* mu  = (unsigned char*)(ws + OFF_MU);
    unsigned char* m1b = (unsigned char*)(ws + OFF_M1);
    short* web3 = (short*)(ws + OFF_WEB3);
    short* wpb3 = (short*)(ws + OFF_WPB3);
    short* gb   = (short*)(ws + OFF_GB);

    float* outF = (float*)d_out;
    float* pre = outF;              // [0:NOUT] pre -> xmT halo -> final out
    float* xm  = outF + NOUT;       // [NOUT:2NOUT] xm -> y (in-place) -> final mask
    short* xmT = (short*)d_out;

    k_wcvt<<<dim3(5904), dim3(256), 0, stream>>>(we, wp, gamma, web3, wpb3, gb);
    k_idwt<<<dim3(B_*C_), dim3(256), 0, stream>>>(ll, b1, b2, b3, llm, m1i, m2i, m3i, pre, mu);
    k_cast<<<dim3(6144), dim3(256), 0, stream>>>(pre, mu, wc, bcast, xm, m1b);
    k_zhalo<<<dim3(194), dim3(256), 0, stream>>>(xmT);
    k_xmt<<<dim3(3072), dim3(256), 0, stream>>>(xm, xmT);
    k_rowsum<<<dim3(B_*H_), dim3(128), 0, stream>>>(m1b, S);
    k_facm<<<dim3(NPIX/256), dim3(256), 0, stream>>>(S, fac, mh);
    k_mbconv<<<dim3(512), dim3(512), 0, stream>>>(xmT, web3, wpb3, be, bp, bcast, fac, mh, m1b, xm);
    k_gdn<<<dim3(256), dim3(512), 0, stream>>>(gb, beta, mh, outF);
}

// Round 11
// 626.830 us; speedup vs baseline: 1.2146x; 1.0138x over previous
//
#include <hip/hip_runtime.h>

#define B_   4
#define C_   192
#define E_   768
#define H0   64
#define H_   128
#define HW   (H_*H_)        // 16384
#define PLANE0 (H0*H0)      // 4096
#define NPIX (B_*HW)        // 65536
#define NOUT (B_*C_*HW)     // 12582912

// halo-padded pixel-major xm: [b][130][130][192] bf16, lives in d_out[0:NOUT]
#define XTW  130
#define XTPL (XTW*XTW)       // 16,900
#define XT_SHORTS (B_*XTPL*192)

// ws layout (bytes)
#define OFF_S    0u
#define OFF_FAC  262144u
#define OFF_MH   524288u
#define OFF_MU   786432u     // u8 3,145,728
#define OFF_M1   3932160u    // u8 12,582,912
#define OFF_WEB3 16515072u   // 108 tiles x [c8 4][e 384][8] bf16 = 2,654,208 (K-major)
#define OFF_WPB3 19169280u   // 12 chunks x [e8 8][co 192][8] bf16 = 294,912 (K-major)
#define OFF_GB   19464192u   // 192*192 bf16 = 73,728
// end 19,537,920

// d_out (2*NOUT f32) timeline:
//   [0:NOUT]      pre (idwt..cast) -> xmT bf16 halo (zhalo..mbconv) -> final out (gdn)
//   [NOUT:2NOUT]  xm f32 (cast..mbconv RMW) -> y -> final mask

typedef __attribute__((ext_vector_type(8))) short bf16x8;
typedef __attribute__((ext_vector_type(4))) float f32x4;

__device__ __forceinline__ unsigned short f2bf(float f) {
    unsigned u = __float_as_uint(f);
    u += 0x7FFFu + ((u >> 16) & 1u);   // RNE
    return (unsigned short)(u >> 16);
}

__device__ __forceinline__ void gll16(const void* g, void* l) {
    __builtin_amdgcn_global_load_lds(
        (const __attribute__((address_space(1))) unsigned int*)g,
        (__attribute__((address_space(3))) unsigned int*)l, 16, 0, 0);
}

// ---------------- K0: zero halo ring of xmT ----------------
__global__ __launch_bounds__(256) void k_zhalo(short* __restrict__ xmT)
{
    int idx = blockIdx.x*256 + threadIdx.x;   // 4 * 516 * 24 = 49,536
    if (idx >= 49536) return;
    int g = idx % 24;
    int pp = (idx / 24) % 516;
    int b = idx / (24*516);
    int i, j;
    if (pp < 130)      { i = 0;   j = pp; }
    else if (pp < 260) { i = 129; j = pp - 130; }
    else { int q = pp - 260; i = 1 + (q >> 1); j = (q & 1) * 129; }
    *(bf16x8*)&xmT[((size_t)(b*XTPL + i*XTW + j))*192 + g*8] = (bf16x8)(short)0;
}

// ---------------- K1: partial IDWT + mask union ----------------
__global__ __launch_bounds__(256) void k_idwt(
    const float* __restrict__ ll, const float* __restrict__ lh,
    const float* __restrict__ hl, const float* __restrict__ hh,
    const int* __restrict__ llm, const int* __restrict__ m1,
    const int* __restrict__ m2, const int* __restrict__ m3,
    float* __restrict__ pre, unsigned char* __restrict__ mu)
{
    const float G0c[7] = {-0.091271763114f,-0.057543526228f,0.591271763114f,1.115087052457f,
                          0.591271763114f,-0.057543526228f,-0.091271763114f};
    const float G1c[9] = {0.026748757411f,0.016864118443f,-0.078223266529f,-0.266864118443f,
                          0.602949018236f,-0.266864118443f,-0.078223266529f,0.016864118443f,
                          0.026748757411f};
    __shared__ float lo[H_*H0];
    __shared__ float hi[H_*H0];
    const int bc = blockIdx.x;
    const int base = bc * PLANE0;
    const int t = threadIdx.x;
    for (int idx = t; idx < H_*H0; idx += 256) {
        int o = idx >> 6, j = idx & 63;
        float alo = 0.f, ahi = 0.f;
        #pragma unroll
        for (int k = 0; k < 7; ++k) {
            int d = o + k - 3;
            if (d >= 0 && d <= 2*H0-2 && !(d & 1)) {
                int q = base + (d >> 1)*H0 + j;
                alo += G0c[k] * ll[q] * (float)llm[q];
                ahi += G0c[k] * hl[q] * (float)m2[q];
            }
        }
        #pragma unroll
        for (int k = 0; k < 9; ++k) {
            int d = o + k - 4;
            if (d >= 0 && d <= 2*H0-2 && !(d & 1)) {
                int q = base + (d >> 1)*H0 + j;
                alo += G1c[k] * lh[q] * (float)m1[q];
                ahi += G1c[k] * hh[q] * (float)m3[q];
            }
        }
        lo[idx] = alo; hi[idx] = ahi;
    }
    for (int idx = t; idx < PLANE0; idx += 256) {
        int q = base + idx;
        mu[q] = (unsigned char)((llm[q] | m1[q] | m2[q] | m3[q]) ? 1 : 0);
    }
    __syncthreads();
    const size_t ob = (size_t)bc * HW;
    for (int idx = t; idx < HW; idx += 256) {
        int o = idx >> 7, q = idx & 127;
        const float* lr = lo + o*H0;
        const float* hr = hi + o*H0;
        float v = 0.f;
        #pragma unroll
        for (int k = 0; k < 7; ++k) {
            int d = q + k - 3;
            if (d >= 0 && d <= 2*H0-2 && !(d & 1)) v += G0c[k] * lr[d >> 1];
        }
        #pragma unroll
        for (int k = 0; k < 9; ++k) {
            int d = q + k - 4;
            if (d >= 0 && d <= 2*H0-2 && !(d & 1)) v += G1c[k] * hr[d >> 1];
        }
        pre[ob + idx] = v;
    }
}

// ---------------- K2: depthwise 3x3 partial conv (cast), LDS-tiled ----------------
__global__ __launch_bounds__(256) void k_cast(
    const float* __restrict__ pre, const unsigned char* __restrict__ mu,
    const float* __restrict__ wc, const float* __restrict__ bcast,
    float* __restrict__ xm, unsigned char* __restrict__ m1out)
{
    __shared__ float sp[18*131];
    __shared__ float smv[10*66];
    const int blk = blockIdx.x;          // 6144 = 768 bc x 8 row-tiles
    const int bc = blk >> 3;
    const int i0 = (blk & 7) * 16;
    const int c = bc % C_;
    const int t = threadIdx.x;
    const size_t pb = (size_t)bc * HW;
    const size_t mb = (size_t)bc * PLANE0;
    for (int q = t; q < 2340; q += 256) {
        int rr = q / 130, cc = q - rr*130;
        int gi = i0 + rr - 1, gj = cc - 1;
        float v = 0.f;
        if ((unsigned)gi < 128u && (unsigned)gj < 128u) v = pre[pb + gi*128 + gj];
        sp[rr*131 + cc] = v;
    }
    for (int q = t; q < 660; q += 256) {
        int rr = q / 66, cc = q - rr*66;
        int mi = (i0 >> 1) + rr - 1, mj = cc - 1;
        float v = 0.f;
        if ((unsigned)mi < 64u && (unsigned)mj < 64u) v = (float)mu[mb + mi*64 + mj];
        smv[rr*66 + cc] = v;
    }
    __syncthreads();
    float w9[9];
    #pragma unroll
    for (int k = 0; k < 9; ++k) w9[k] = wc[c*9 + k];
    const float bcc = bcast[c];
    const int rr = t >> 4, c8 = (t & 15) * 8;
    float ox[8]; unsigned mo = 0, mo2 = 0;
    #pragma unroll
    for (int u = 0; u < 8; ++u) {
        int j = c8 + u;
        float o = 0.f, s = 0.f;
        #pragma unroll
        for (int di = 0; di < 3; ++di) {
            int gi = i0 + rr + di - 1;
            int mrow = (gi >> 1) - (i0 >> 1) + 1;
            #pragma unroll
            for (int dj = 0; dj < 3; ++dj) {
                int gj = j + dj - 1;
                float m0v = smv[mrow*66 + (gj >> 1) + 1];
                s += m0v;
                o += m0v * sp[(rr+di)*131 + j + dj] * w9[di*3 + dj];
            }
        }
        bool valid = s > 0.f;
        ox[u] = valid ? (o * (9.f / s) + bcc) : 0.f;
        unsigned bit = valid ? 1u : 0u;
        if (u < 4) mo |= bit << (8*u); else mo2 |= bit << (8*(u-4));
    }
    size_t oidx = pb + (size_t)(i0 + rr)*128 + c8;
    f32x4 v0 = {ox[0], ox[1], ox[2], ox[3]};
    f32x4 v1 = {ox[4], ox[5], ox[6], ox[7]};
    *(f32x4*)&xm[oidx] = v0;
    *(f32x4*)&xm[oidx + 4] = v1;
    *(unsigned*)&m1out[oidx] = mo;
    *(unsigned*)&m1out[oidx + 4] = mo2;
}

// ---------------- K3: channel-sum of mask1 (2-way split + LDS combine) ----------------
__global__ __launch_bounds__(256) void k_rowsum(const unsigned char* __restrict__ m1,
                                                float* __restrict__ S)
{
    __shared__ float red[128];
    int bi = blockIdx.x;                // b*128 + i
    int b = bi >> 7, i = bi & 127;
    int t = threadIdx.x;
    int j = t & 127, half = t >> 7;
    float s = 0.f;
    size_t base = (size_t)b*C_*HW + (size_t)(half*96)*HW + (size_t)i*H_ + j;
    for (int c = 0; c < 96; ++c) s += (float)m1[base + (size_t)c*HW];
    if (half) red[j] = s;
    __syncthreads();
    if (!half) S[bi*H_ + j] = s + red[j];
}

// ---------------- K4: window-sum -> expand factor & mh ----------------
__global__ __launch_bounds__(256) void k_facm(const float* __restrict__ S,
                                              float* __restrict__ fac, float* __restrict__ mh)
{
    int px = blockIdx.x*256 + threadIdx.x;
    if (px >= NPIX) return;
    int j = px & 127, i = (px >> 7) & 127, b = px >> 14;
    float w3 = 0.f;
    #pragma unroll
    for (int di = -1; di <= 1; ++di) {
        int gi = i + di; if ((unsigned)gi >= (unsigned)H_) continue;
        #pragma unroll
        for (int dj = -1; dj <= 1; ++dj) {
            int gj = j + dj; if ((unsigned)gj >= (unsigned)H_) continue;
            w3 += S[(b*H_ + gi)*H_ + gj];
        }
    }
    bool v = w3 > 0.f;
    fac[px] = v ? 1728.f / w3 : 0.f;
    mh[px]  = v ? 1.f : 0.f;
}

// ---------------- K4b: weight convert + permute (K-major, no swizzle) ----------------
// web3: tile = p*54 + sc*9 + r, layout [c8 4][e 384][j 8]:
//   value = we[(p*384+e)*1728 + (sc*32 + c8*8 + j)*9 + r]
// wpb3: chunk = p*6+ec, layout [e8 8][co 192][j 8]:
//   value = wp[co*768 + chunk*64 + e8*8 + j]
// gb  : gamma bf16 [co][c]
__global__ __launch_bounds__(256) void k_wcvt(const float* __restrict__ we,
                                              const float* __restrict__ wp,
                                              const float* __restrict__ gamma,
                                              short* __restrict__ web3,
                                              short* __restrict__ wpb3,
                                              short* __restrict__ gb)
{
    int idx = blockIdx.x*256 + threadIdx.x;
    const int N1 = 108*12288;        // 1,327,104
    const int N2 = 12*12288;         // 147,456
    if (idx < N1) {
        int tile = idx / 12288, rem = idx % 12288;
        int g = rem >> 3, j = rem & 7;
        int c8 = g / 384, e = g % 384;
        int p = tile / 54, sc = (tile % 54) / 9, r = tile % 9;
        web3[idx] = (short)f2bf(we[(size_t)(p*384 + e)*1728 + (sc*32 + c8*8 + j)*9 + r]);
    } else if (idx < N1 + N2) {
        int i2 = idx - N1;
        int chunk = i2 / 12288, rem = i2 % 12288;
        int g = rem >> 3, j = rem & 7;
        int e8 = g / 192, co = g % 192;
        wpb3[i2] = (short)f2bf(wp[(size_t)co*E_ + chunk*64 + e8*8 + j]);
    } else {
        int i3 = idx - N1 - N2;
        if (i3 < C_*C_) gb[i3] = (short)f2bf(gamma[i3]);
    }
}

// ---------------- K4c: xm f32 [c][pix] -> xmT bf16 [b][130][130][192] (interior) ----------------
__global__ __launch_bounds__(256) void k_xmt(const float* __restrict__ xm,
                                             short* __restrict__ xmT)
{
    __shared__ float sm[64*65];
    const int gx = blockIdx.x;           // 3072 = 3 cb * 1024 pb
    const int cb = gx >> 10, pb = gx & 1023;
    const int c0 = cb*64, pix0 = pb*64;
    const int b = pix0 >> 14, pixb = pix0 & 16383;
    const int t = threadIdx.x;
    const int lane6 = t & 63, hi4 = t >> 6;
    #pragma unroll
    for (int it = 0; it < 16; ++it) {
        int r4 = it*4 + hi4;
        sm[r4*65 + lane6] = xm[((size_t)(b*C_ + c0 + r4))*HW + pixb + lane6];
    }
    __syncthreads();
    #pragma unroll
    for (int it = 0; it < 2; ++it) {
        int q = it*256 + t;
        int pp = q >> 3, c8 = q & 7;
        int p = pixb + pp;
        int i = p >> 7, j = p & 127;
        bf16x8 v;
        #pragma unroll
        for (int jj = 0; jj < 8; ++jj) v[jj] = (short)f2bf(sm[(c8*8+jj)*65 + pp]);
        *(bf16x8*)&xmT[((size_t)(b*XTPL + (i+1)*XTW + (j+1)))*192 + c0 + c8*8] = v;
    }
}

// ---------------- K5: MFMA fused MBConv — K-major LDS, unrolled taps, dbuf apat ----------------
// 512 blocks x 512 thr (8 waves, 2m x 4e). 2 e-passes of 384; per pass 54 taps.
// All MFMA-operand LDS reads: per-thread invariant base + compile-time immediate. No XOR.
__global__ __launch_bounds__(512, 1) void k_mbconv(
    const short* __restrict__ xmT, const short* __restrict__ web3,
    const short* __restrict__ wpb3, const float* __restrict__ be,
    const float* __restrict__ bp, const float* __restrict__ bcast,
    const float* __restrict__ fac, const float* __restrict__ mh,
    const unsigned char* __restrict__ m1, float* __restrict__ xmy)
{
    __shared__ __align__(16) char smem[147456];
    // expand: apat @0 [2][c8 4][pos 180][8] 23,040 | bB @23,040 [3][c8 4][e 384][8] 73,728 (ends 96,768)
    // proj:   wpB @0 [2][e8 8][co 192][8] 49,152 | hB @49,152 [e8 48][px 128][8] 98,304 (ends 147,456)
    // epi:    fbuf @0 [192][132] f32 101,376
    short* apat = (short*)smem;
    short* bB   = (short*)(smem + 23040);
    short* wpB  = (short*)smem;
    short* hB   = (short*)(smem + 49152);
    float* fbuf = (float*)smem;

    // XCD-aware swizzle: 512 blocks = 8 XCDs x 64 contiguous
    const int blk = (blockIdx.x & 7)*64 + (blockIdx.x >> 3);
    const int b = blk >> 7;                       // 4b x 16ti x 8tj
    const int ti = (blk >> 3) & 15, tj = blk & 7;
    const int i0 = ti*8, j0 = tj*16;              // tile = 8 rows x 16 cols
    const int t = threadIdx.x;
    const int w = t >> 6, l = t & 63;
    const int wm2 = w >> 2, we2 = w & 3;
    const int m0 = wm2 * 64;
    const int lo = l & 15, hi = l >> 4;

// A-patch staging: 720 granules = [c8 4][pos 180]; 512 + 192 full-wave gll + 16 scalar tail.
#define ISSUE_A(sc_, buf_) do {                                                 \
    const int c0_ = (sc_)*32;                                                   \
    {   int q_ = t;                                                             \
        int c8_ = q_ / 180, pos_ = q_ - c8_*180;                                \
        int rr_ = pos_/18, cc_ = pos_ - rr_*18;                                 \
        gll16(&xmT[((size_t)(b*XTPL + (i0+rr_)*XTW + (j0+cc_)))*192 + c0_       \
                   + c8_*8], &apat[(buf_)*5760 + q_*8]);                        \
    }                                                                           \
    if (t < 192) {                                                              \
        int q_ = 512 + t;                                                       \
        int c8_ = q_ / 180, pos_ = q_ - c8_*180;                                \
        int rr_ = pos_/18, cc_ = pos_ - rr_*18;                                 \
        gll16(&xmT[((size_t)(b*XTPL + (i0+rr_)*XTW + (j0+cc_)))*192 + c0_       \
                   + c8_*8], &apat[(buf_)*5760 + q_*8]);                        \
    }                                                                           \
    if (t < 16) {                                                               \
        int q_ = 704 + t;                                                       \
        int pos_ = q_ - 540;             /* c8 = 3 */                           \
        int rr_ = pos_/18, cc_ = pos_ - rr_*18;                                 \
        bf16x8 v_ = *(const bf16x8*)&xmT[((size_t)(b*XTPL + (i0+rr_)*XTW        \
                   + (j0+cc_)))*192 + c0_ + 24];                                \
        *(bf16x8*)&apat[(buf_)*5760 + q_*8] = v_;                               \
    }                                                                           \
} while(0)

#define ISSUE_B(tileIdx_, bufIdx_) do {                                         \
    const size_t off_ = (size_t)(tileIdx_) * 12288;                             \
    short* dst_ = &bB[(bufIdx_) * 12288];                                       \
    for (int it_ = 0; it_ < 3; ++it_) {                                         \
        int q_ = it_*512 + t;                                                   \
        gll16(&web3[off_ + q_*8], &dst_[q_*8]);                                 \
    }                                                                           \
} while(0)

#define ISSUE_WP(chunkIdx_, bufIdx_) do {                                       \
    const size_t off_ = (size_t)(chunkIdx_) * 12288;                            \
    short* dst_ = &wpB[(bufIdx_) * 12288];                                      \
    for (int it_ = 0; it_ < 3; ++it_) {                                         \
        int q_ = it_*512 + t;                                                   \
        gll16(&wpb3[off_ + q_*8], &dst_[q_*8]);                                 \
    }                                                                           \
} while(0)

#define WAITBAR(N_) do {                                                        \
    asm volatile("s_waitcnt vmcnt(" #N_ ") lgkmcnt(0)" ::: "memory");           \
    __builtin_amdgcn_s_barrier();                                               \
    __builtin_amdgcn_sched_barrier(0);                                          \
} while(0)

#define LGKMBAR() do {                                                          \
    asm volatile("s_waitcnt lgkmcnt(0)" ::: "memory");                          \
    __builtin_amdgcn_s_barrier();                                               \
    __builtin_amdgcn_sched_barrier(0);                                          \
} while(0)

    float facr[4][4];
    #pragma unroll
    for (int af = 0; af < 4; ++af)
        #pragma unroll
        for (int reg = 0; reg < 4; ++reg) {
            int px = m0 + af*16 + hi*4 + reg;
            facr[af][reg] = fac[b*HW + (i0 + (px >> 4))*128 + j0 + (px & 15)];
        }
    // per-thread invariant LDS bases (short indices)
    int aoffS[4], boffS[6], hbaseS[4], wbaseS[3];
    #pragma unroll
    for (int af = 0; af < 4; ++af) {
        int px = m0 + af*16 + lo;
        aoffS[af] = (hi*180 + (px >> 4)*18 + (px & 15)) * 8;
        hbaseS[af] = (hi*128 + px) * 8;
    }
    #pragma unroll
    for (int nf = 0; nf < 6; ++nf)
        boffS[nf] = (hi*384 + we2*96 + nf*16 + lo) * 8;
    #pragma unroll
    for (int nf = 0; nf < 3; ++nf)
        wbaseS[nf] = (hi*192 + we2*48 + nf*16 + lo) * 8;

    // prologue
    ISSUE_A(0, 0);
    ISSUE_B(0, 0);
    ISSUE_B(1, 1);

    #pragma unroll 1
    for (int p = 0; p < 2; ++p) {
        // ================= expand: 54 taps (6 sc x 9 unrolled) =================
        f32x4 acc[4][6];
        #pragma unroll
        for (int a = 0; a < 4; ++a)
            #pragma unroll
            for (int n = 0; n < 6; ++n) acc[a][n] = (f32x4){0.f,0.f,0.f,0.f};

        #pragma unroll 1
        for (int sc = 0; sc < 6; ++sc) {
            const int abufS = (sc & 1) * 5760;
            const int tbase = p*54 + sc*9;
            #pragma unroll
            for (int r = 0; r < 9; ++r) {
                const int tm = r % 3;                       // compile-time
                const int d2 = (r + 2) % 3;                 // compile-time
                const int rv = (r/3)*18 + (r%3);            // compile-time
                // schedule: uniform single WAITBAR(3); last two taps drain
                if (sc < 5 || r < 7) {
                    WAITBAR(3);
                    if (r == 0 && sc < 5) ISSUE_A(sc + 1, (sc + 1) & 1);
                    ISSUE_B(tbase + r + 2, d2);
                } else if (r == 7) {
                    WAITBAR(3);
                } else {
                    WAITBAR(0);
                }
                const short* bcur = &bB[tm * 12288];
                bf16x8 a[4], bb[6];
                #pragma unroll
                for (int af = 0; af < 4; ++af)
                    a[af] = *(const bf16x8*)&apat[abufS + aoffS[af] + rv*8];
                #pragma unroll
                for (int nf = 0; nf < 6; ++nf)
                    bb[nf] = *(const bf16x8*)&bcur[boffS[nf]];
                __builtin_amdgcn_s_setprio(1);
                #pragma unroll
                for (int af = 0; af < 4; ++af)
                    #pragma unroll
                    for (int nf = 0; nf < 6; ++nf)
                        acc[af][nf] = __builtin_amdgcn_mfma_f32_16x16x32_bf16(
                            a[af], bb[nf], acc[af][nf], 0, 0, 0);
                __builtin_amdgcn_s_setprio(0);
            }
        }

        // ================= silu -> hB =================
        LGKMBAR();                         // tap-53 reads done; apat/bB dead
        ISSUE_WP(p*6, 0);
        #pragma unroll
        for (int nf = 0; nf < 6; ++nf) {
            int e_loc = we2*96 + nf*16 + lo;
            float bev = be[p*384 + e_loc];
            int hb = (e_loc >> 3)*1024 + (e_loc & 7);
            #pragma unroll
            for (int af = 0; af < 4; ++af)
                #pragma unroll
                for (int reg = 0; reg < 4; ++reg) {
                    int px = m0 + af*16 + hi*4 + reg;
                    float fr = facr[af][reg];
                    float v = acc[af][nf][reg]*fr + bev;
                    float hv = (fr > 0.f) ? v / (1.f + __expf(-v)) : 0.f;
                    hB[hb + px*8] = (short)f2bf(hv);
                }
        }

        // ================= proj: 6 chunks of 64 e =================
        f32x4 accy[4][3];
        #pragma unroll
        for (int a = 0; a < 4; ++a)
            #pragma unroll
            for (int n = 0; n < 3; ++n) accy[a][n] = (f32x4){0.f,0.f,0.f,0.f};

        LGKMBAR();                         // silu hB writes visible to all
        #pragma unroll 1
        for (int ec = 0; ec < 6; ++ec) {
            if (ec > 0) LGKMBAR();         // prev-prev wpB buf reads done before restage
            if (ec < 5) {
                ISSUE_WP(p*6 + ec + 1, (ec + 1) & 1);
                asm volatile("s_waitcnt vmcnt(3) lgkmcnt(0)" ::: "memory");
            } else {
                asm volatile("s_waitcnt vmcnt(0) lgkmcnt(0)" ::: "memory");
            }
            __builtin_amdgcn_s_barrier();
            __builtin_amdgcn_sched_barrier(0);
            const short* wcur = &wpB[(ec & 1) * 12288];
            const short* hcur = &hB[ec * 8192];
            #pragma unroll
            for (int ks = 0; ks < 2; ++ks) {
                bf16x8 a[4], bb[3];
                #pragma unroll
                for (int af = 0; af < 4; ++af)
                    a[af] = *(const bf16x8*)&hcur[ks*4096 + hbaseS[af]];
                #pragma unroll
                for (int nf = 0; nf < 3; ++nf)
                    bb[nf] = *(const bf16x8*)&wcur[ks*6144 + wbaseS[nf]];
                __builtin_amdgcn_s_setprio(1);
                #pragma unroll
                for (int af = 0; af < 4; ++af)
                    #pragma unroll
                    for (int nf = 0; nf < 3; ++nf)
                        accy[af][nf] = __builtin_amdgcn_mfma_f32_16x16x32_bf16(
                            a[af], bb[nf], accy[af][nf], 0, 0, 0);
                __builtin_amdgcn_s_setprio(0);
            }
        }

        // ================= per-pass y accumulate (single fbuf phase) =================
        LGKMBAR();                         // proj reads done; hB/wpB dead
        #pragma unroll
        for (int af = 0; af < 4; ++af)
            #pragma unroll
            for (int nf = 0; nf < 3; ++nf) {
                int co = we2*48 + nf*16 + lo;
                int pxl = m0 + af*16 + hi*4;
                *(f32x4*)&fbuf[co*132 + pxl] = accy[af][nf];
            }
        __syncthreads();
        #pragma unroll 1
        for (int it = 0; it < 12; ++it) {
            int q = it*512 + t;              // 6144 = 192co x 32 px-quads
            int co = q >> 5, px4 = (q & 31) << 2;
            int pi = px4 >> 4, pj = px4 & 15;
            size_t gidx = ((size_t)(b*C_ + co))*HW + (size_t)(i0+pi)*128 + j0 + pj;
            f32x4 pv = *(f32x4*)&fbuf[co*132 + px4];
            f32x4 prev = *(const f32x4*)&xmy[gidx];
            f32x4 o;
            if (p == 0) {
                int pixg = b*HW + (i0+pi)*128 + j0 + pj;
                f32x4 mh4 = *(const f32x4*)&mh[pixg];
                unsigned mu4 = *(const unsigned*)&m1[gidx];
                float bpc = bp[co], bcc = bcast[co];
                #pragma unroll
                for (int k = 0; k < 4; ++k)
                    o[k] = pv[k] + bpc + prev[k] + bcc*(mh4[k] - (float)((mu4 >> (8*k)) & 255u));
            } else {
                #pragma unroll
                for (int k = 0; k < 4; ++k) o[k] = prev[k] + pv[k];
            }
            *(f32x4*)&xmy[gidx] = o;
        }
        __syncthreads();
        if (p == 0) { ISSUE_A(0, 0); ISSUE_B(54, 0); ISSUE_B(55, 1); }
    }
#undef ISSUE_A
#undef ISSUE_B
#undef ISSUE_WP
#undef WAITBAR
#undef LGKMBAR
}

// ---------------- K6: MFMA GDN, 2x128 px tiles ----------------
__global__ __launch_bounds__(512, 2) void k_gdn(
    const short* __restrict__ gb, const float* __restrict__ beta,
    const float* __restrict__ mh, float* __restrict__ dout)
{
    __shared__ __align__(16) char smem[101376];
    short* aB = (short*)smem;               // [256][104] 53,248
    short* bG = (short*)(smem + 53248);     // [192][104] 39,936
    float* fbuf = (float*)smem;             // [192][132]
    const float* y = dout + NOUT;

    const int blk = blockIdx.x;             // 256 = 4b * 64 row-pairs
    const int b = blk >> 6;
    const int row0 = (blk & 63) * 2;
    const int t = threadIdx.x;
    const int w = t >> 6, l = t & 63;
    const int wm = w >> 1, we_ = w & 1;
    const int m0 = wm * 64;
    const int lo = l & 15, hi = l >> 4;

    f32x4 acc[4][6];
    #pragma unroll
    for (int a = 0; a < 4; ++a)
        #pragma unroll
        for (int n = 0; n < 6; ++n) acc[a][n] = (f32x4){0.f,0.f,0.f,0.f};

    #pragma unroll 1
    for (int ch = 0; ch < 2; ++ch) {
        __syncthreads();
        #pragma unroll 1
        for (int it = 0; it < 12; ++it) {
            int q = it*512 + t;                 // 6144 = 96c x 64 px-chunks
            int cL = q >> 6, px4 = (q & 63) << 2;
            int c = ch*96 + cL;
            int pi = px4 >> 7, pj = px4 & 127;
            f32x4 yv = *(const f32x4*)&y[((size_t)(b*C_ + c))*HW + (size_t)(row0+pi)*128 + pj];
            #pragma unroll
            for (int k = 0; k < 4; ++k)
                aB[(px4+k)*104 + cL] = (short)f2bf(yv[k]*yv[k]);
        }
        #pragma unroll 1
        for (int it = 0; it < 5; ++it) {
            int q = it*512 + t;
            if (q < 2304) {
                int co = q / 12, e8 = q - co*12;
                *(bf16x8*)&bG[co*104 + e8*8] = *(const bf16x8*)&gb[co*192 + ch*96 + e8*8];
            }
        }
        __syncthreads();
        #pragma unroll
        for (int ks = 0; ks < 3; ++ks) {
            const int koff = ks*32 + hi*8;
            bf16x8 a[4], bb[6];
            #pragma unroll
            for (int af = 0; af < 4; ++af)
                a[af] = *(const bf16x8*)&aB[(m0 + af*16 + lo)*104 + koff];
            #pragma unroll
            for (int nf = 0; nf < 6; ++nf)
                bb[nf] = *(const bf16x8*)&bG[(we_*96 + nf*16 + lo)*104 + koff];
            #pragma unroll
            for (int af = 0; af < 4; ++af)
                #pragma unroll
                for (int nf = 0; nf < 6; ++nf)
                    acc[af][nf] = __builtin_amdgcn_mfma_f32_16x16x32_bf16(
                        a[af], bb[nf], acc[af][nf], 0, 0, 0);
        }
    }

    #pragma unroll 1
    for (int ph = 0; ph < 2; ++ph) {
        __syncthreads();
        if ((wm >> 1) == ph) {
            #pragma unroll
            for (int af = 0; af < 4; ++af)
                #pragma unroll
                for (int nf = 0; nf < 6; ++nf) {
                    int co = we_*96 + nf*16 + lo;
                    int pxl = (wm&1)*64 + af*16 + hi*4;
                    *(f32x4*)&fbuf[co*132 + pxl] = acc[af][nf];
                }
        }
        __syncthreads();
        #pragma unroll 1
        for (int it = 0; it < 12; ++it) {
            int q = it*512 + t;
            int co = q >> 5, px4 = (q & 31) << 2;
            size_t gidx = ((size_t)(b*C_ + co))*HW + (size_t)(row0+ph)*128 + px4;
            int pixg = b*HW + (row0+ph)*128 + px4;
            f32x4 nv = *(f32x4*)&fbuf[co*132 + px4];
            f32x4 yv = *(const f32x4*)&y[gidx];
            f32x4 mh4 = *(const f32x4*)&mh[pixg];
            float bt = beta[co];
            f32x4 o;
            #pragma unroll
            for (int k = 0; k < 4; ++k)
                o[k] = (mh4[k] > 0.f) ? yv[k]*rsqrtf(bt + nv[k]) : 0.f;
            *(f32x4*)&dout[gidx] = o;
            *(f32x4*)&dout[(size_t)NOUT + gidx] = mh4;   // final mask (y read above)
        }
    }
}

extern "C" void kernel_launch(void* const* d_in, const int* in_sizes, int n_in,
                              void* d_out, int out_size, void* d_ws, size_t ws_size,
                              hipStream_t stream)
{
    const float* ll = (const float*)d_in[0];
    const float* b1 = (const float*)d_in[1];
    const float* b2 = (const float*)d_in[2];
    const float* b3 = (const float*)d_in[3];
    const int* llm = (const int*)d_in[4];
    const int* m1i = (const int*)d_in[5];
    const int* m2i = (const int*)d_in[6];
    const int* m3i = (const int*)d_in[7];
    const float* wc    = (const float*)d_in[8];
    const float* bcast = (const float*)d_in[9];
    const float* we    = (const float*)d_in[10];
    const float* be    = (const float*)d_in[11];
    const float* wp    = (const float*)d_in[12];
    const float* bp    = (const float*)d_in[13];
    const float* gamma = (const float*)d_in[14];
    const float* beta  = (const float*)d_in[15];

    char* ws = (char*)d_ws;
    float* S   = (float*)(ws + OFF_S);
    float* fac = (float*)(ws + OFF_FAC);
    float* mh  = (float*)(ws + OFF_MH);
    unsigned char* mu  = (unsigned char*)(ws + OFF_MU);
    unsigned char* m1b = (unsigned char*)(ws + OFF_M1);
    short* web3 = (short*)(ws + OFF_WEB3);
    short* wpb3 = (short*)(ws + OFF_WPB3);
    short* gb   = (short*)(ws + OFF_GB);

    float* outF = (float*)d_out;
    float* pre = outF;              // [0:NOUT] pre -> xmT halo -> final out
    float* xm  = outF + NOUT;       // [NOUT:2NOUT] xm -> y (in-place) -> final mask
    short* xmT = (short*)d_out;

    k_wcvt<<<dim3(5904), dim3(256), 0, stream>>>(we, wp, gamma, web3, wpb3, gb);
    k_idwt<<<dim3(B_*C_), dim3(256), 0, stream>>>(ll, b1, b2, b3, llm, m1i, m2i, m3i, pre, mu);
    k_cast<<<dim3(6144), dim3(256), 0, stream>>>(pre, mu, wc, bcast, xm, m1b);
    k_zhalo<<<dim3(194), dim3(256), 0, stream>>>(xmT);
    k_xmt<<<dim3(3072), dim3(256), 0, stream>>>(xm, xmT);
    k_rowsum<<<dim3(B_*H_), dim3(256), 0, stream>>>(m1b, S);
    k_facm<<<dim3(NPIX/256), dim3(256), 0, stream>>>(S, fac, mh);
    k_mbconv<<<dim3(512), dim3(512), 0, stream>>>(xmT, web3, wpb3, be, bp, bcast, fac, mh, m1b, xm);
    k_gdn<<<dim3(256), dim3(512), 0, stream>>>(gb, beta, mh, outF);
}

// Round 12
// 466.008 us; speedup vs baseline: 1.6338x; 1.3451x over previous
//
#include <hip/hip_runtime.h>

#define B_   4
#define C_   192
#define E_   768
#define H0   64
#define H_   128
#define HW   (H_*H_)        // 16384
#define PLANE0 (H0*H0)      // 4096
#define NPIX (B_*HW)        // 65536
#define NOUT (B_*C_*HW)     // 12582912

// halo-padded pixel-major xm: [b][130][130][192] bf16, lives in d_out[0:NOUT]
#define XTW  130
#define XTPL (XTW*XTW)       // 16,900
#define XT_SHORTS (B_*XTPL*192)

// ws layout (bytes)
#define OFF_S    0u
#define OFF_FAC  262144u
#define OFF_MH   524288u
#define OFF_MU   786432u     // u8 3,145,728
#define OFF_M1   3932160u    // u8 12,582,912
#define OFF_WEB3 16515072u   // 108 tiles x [c8 4][e 384][8] bf16 = 2,654,208 (K-major)
#define OFF_WPB3 19169280u   // 12 chunks x [e8 8][co 192][8] bf16 = 294,912 (K-major)
#define OFF_GB   19464192u   // 192*192 bf16 = 73,728
// end 19,537,920

// d_out (2*NOUT f32) timeline:
//   [0:NOUT]      pre (idwt..cast) -> xmT bf16 halo (zhalo..mbconv) -> final out (gdn)
//   [NOUT:2NOUT]  xm f32 (cast..mbconv RMW) -> y -> final mask

typedef __attribute__((ext_vector_type(8))) short bf16x8;
typedef __attribute__((ext_vector_type(4))) float f32x4;

__device__ __forceinline__ unsigned short f2bf(float f) {
    unsigned u = __float_as_uint(f);
    u += 0x7FFFu + ((u >> 16) & 1u);   // RNE
    return (unsigned short)(u >> 16);
}

__device__ __forceinline__ void gll16(const void* g, void* l) {
    __builtin_amdgcn_global_load_lds(
        (const __attribute__((address_space(1))) unsigned int*)g,
        (__attribute__((address_space(3))) unsigned int*)l, 16, 0, 0);
}

// ---------------- K0: zero halo ring of xmT ----------------
__global__ __launch_bounds__(256) void k_zhalo(short* __restrict__ xmT)
{
    int idx = blockIdx.x*256 + threadIdx.x;   // 4 * 516 * 24 = 49,536
    if (idx >= 49536) return;
    int g = idx % 24;
    int pp = (idx / 24) % 516;
    int b = idx / (24*516);
    int i, j;
    if (pp < 130)      { i = 0;   j = pp; }
    else if (pp < 260) { i = 129; j = pp - 130; }
    else { int q = pp - 260; i = 1 + (q >> 1); j = (q & 1) * 129; }
    *(bf16x8*)&xmT[((size_t)(b*XTPL + i*XTW + j))*192 + g*8] = (bf16x8)(short)0;
}

// ---------------- K1: partial IDWT + mask union (8 waves, parity-specialized) ----------------
__global__ __launch_bounds__(512) void k_idwt(
    const float* __restrict__ ll, const float* __restrict__ lh,
    const float* __restrict__ hl, const float* __restrict__ hh,
    const int* __restrict__ llm, const int* __restrict__ m1,
    const int* __restrict__ m2, const int* __restrict__ m3,
    float* __restrict__ pre, unsigned char* __restrict__ mu)
{
    // G0 (7-tap), G1 (9-tap) synthesis coefficients
    const float G0c[7] = {-0.091271763114f,-0.057543526228f,0.591271763114f,1.115087052457f,
                          0.591271763114f,-0.057543526228f,-0.091271763114f};
    const float G1c[9] = {0.026748757411f,0.016864118443f,-0.078223266529f,-0.266864118443f,
                          0.602949018236f,-0.266864118443f,-0.078223266529f,0.016864118443f,
                          0.026748757411f};
    __shared__ float lo[H_*H0];   // 32 KB
    __shared__ float hi[H_*H0];   // 32 KB
    const int bc = blockIdx.x;
    const int base = bc * PLANE0;
    const int t = threadIdx.x;
    const int w = t >> 6, lane = t & 63;

    // ---- vertical synthesis: o wave-uniform, parity branches uniform ----
    #pragma unroll 1
    for (int iter = 0; iter < 16; ++iter) {
        const int o = iter*8 + w;
        float alo = 0.f, ahi = 0.f;
        if (o & 1) {
            // G0 k=2s (d=o-3+2s), G1 k=2s+1 (same d), s=0..3
            #pragma unroll
            for (int s = 0; s < 4; ++s) {
                int d = o - 3 + 2*s;
                if ((unsigned)d <= 126u) {
                    int q = base + (d >> 1)*H0 + lane;
                    float g0 = G0c[2*s], g1 = G1c[2*s + 1];
                    alo += g0 * ll[q]*(float)llm[q] + g1 * lh[q]*(float)m1[q];
                    ahi += g0 * hl[q]*(float)m2[q] + g1 * hh[q]*(float)m3[q];
                }
            }
        } else {
            // G1 k=2s (d=o-4+2s, s=0..4); G0 k=2s-1 for s=1..3 (same d)
            #pragma unroll
            for (int s = 0; s < 5; ++s) {
                int d = o - 4 + 2*s;
                if ((unsigned)d <= 126u) {
                    int q = base + (d >> 1)*H0 + lane;
                    float g1 = G1c[2*s];
                    alo += g1 * lh[q]*(float)m1[q];
                    ahi += g1 * hh[q]*(float)m3[q];
                    if (s >= 1 && s <= 3) {
                        float g0 = G0c[2*s - 1];
                        alo += g0 * ll[q]*(float)llm[q];
                        ahi += g0 * hl[q]*(float)m2[q];
                    }
                }
            }
        }
        lo[o*H0 + lane] = alo;
        hi[o*H0 + lane] = ahi;
    }
    // mask union (u8)
    for (int idx = t; idx < PLANE0; idx += 512) {
        int q = base + idx;
        mu[q] = (unsigned char)((llm[q] | m1[q] | m2[q] | m3[q]) ? 1 : 0);
    }
    __syncthreads();

    // ---- horizontal synthesis: lane c computes output pair (2c, 2c+1); float2 store ----
    const size_t ob = (size_t)bc * HW;
    const int c = lane;
    #pragma unroll 1
    for (int iter = 0; iter < 16; ++iter) {
        const int o = iter*8 + w;
        const float* lr = lo + o*H0;
        const float* hr = hi + o*H0;
        float lC  = lr[c];
        float hC  = hr[c];
        float lM1 = (c >= 1)  ? lr[c-1] : 0.f;
        float lP1 = (c <= 62) ? lr[c+1] : 0.f;
        float lP2 = (c <= 61) ? lr[c+2] : 0.f;
        float hM2 = (c >= 2)  ? hr[c-2] : 0.f;
        float hM1 = (c >= 1)  ? hr[c-1] : 0.f;
        float hP1 = (c <= 62) ? hr[c+1] : 0.f;
        float hP2 = (c <= 61) ? hr[c+2] : 0.f;
        // even q=2c: G0 taps idx c-1..c+1 (k=1,3,5); G1 taps idx c-2..c+2 (k=0,2,4,6,8)
        float pe = G0c[1]*lM1 + G0c[3]*lC + G0c[5]*lP1
                 + G1c[0]*hM2 + G1c[2]*hM1 + G1c[4]*hC + G1c[6]*hP1 + G1c[8]*hP2;
        // odd q=2c+1: G0 taps idx c-1..c+2 (k=0,2,4,6); G1 taps idx c-1..c+2 (k=1,3,5,7)
        float po = G0c[0]*lM1 + G0c[2]*lC + G0c[4]*lP1 + G0c[6]*lP2
                 + G1c[1]*hM1 + G1c[3]*hC + G1c[5]*hP1 + G1c[7]*hP2;
        float2 pv = {pe, po};
        *(float2*)&pre[ob + (size_t)o*H_ + 2*c] = pv;
    }
}

// ---------------- K2: depthwise 3x3 partial conv (cast), LDS-tiled ----------------
__global__ __launch_bounds__(256) void k_cast(
    const float* __restrict__ pre, const unsigned char* __restrict__ mu,
    const float* __restrict__ wc, const float* __restrict__ bcast,
    float* __restrict__ xm, unsigned char* __restrict__ m1out)
{
    __shared__ float sp[18*131];
    __shared__ float smv[10*66];
    const int blk = blockIdx.x;          // 6144 = 768 bc x 8 row-tiles
    const int bc = blk >> 3;
    const int i0 = (blk & 7) * 16;
    const int c = bc % C_;
    const int t = threadIdx.x;
    const size_t pb = (size_t)bc * HW;
    const size_t mb = (size_t)bc * PLANE0;
    for (int q = t; q < 2340; q += 256) {
        int rr = q / 130, cc = q - rr*130;
        int gi = i0 + rr - 1, gj = cc - 1;
        float v = 0.f;
        if ((unsigned)gi < 128u && (unsigned)gj < 128u) v = pre[pb + gi*128 + gj];
        sp[rr*131 + cc] = v;
    }
    for (int q = t; q < 660; q += 256) {
        int rr = q / 66, cc = q - rr*66;
        int mi = (i0 >> 1) + rr - 1, mj = cc - 1;
        float v = 0.f;
        if ((unsigned)mi < 64u && (unsigned)mj < 64u) v = (float)mu[mb + mi*64 + mj];
        smv[rr*66 + cc] = v;
    }
    __syncthreads();
    float w9[9];
    #pragma unroll
    for (int k = 0; k < 9; ++k) w9[k] = wc[c*9 + k];
    const float bcc = bcast[c];
    const int rr = t >> 4, c8 = (t & 15) * 8;
    float ox[8]; unsigned mo = 0, mo2 = 0;
    #pragma unroll
    for (int u = 0; u < 8; ++u) {
        int j = c8 + u;
        float o = 0.f, s = 0.f;
        #pragma unroll
        for (int di = 0; di < 3; ++di) {
            int gi = i0 + rr + di - 1;
            int mrow = (gi >> 1) - (i0 >> 1) + 1;
            #pragma unroll
            for (int dj = 0; dj < 3; ++dj) {
                int gj = j + dj - 1;
                float m0v = smv[mrow*66 + (gj >> 1) + 1];
                s += m0v;
                o += m0v * sp[(rr+di)*131 + j + dj] * w9[di*3 + dj];
            }
        }
        bool valid = s > 0.f;
        ox[u] = valid ? (o * (9.f / s) + bcc) : 0.f;
        unsigned bit = valid ? 1u : 0u;
        if (u < 4) mo |= bit << (8*u); else mo2 |= bit << (8*(u-4));
    }
    size_t oidx = pb + (size_t)(i0 + rr)*128 + c8;
    f32x4 v0 = {ox[0], ox[1], ox[2], ox[3]};
    f32x4 v1 = {ox[4], ox[5], ox[6], ox[7]};
    *(f32x4*)&xm[oidx] = v0;
    *(f32x4*)&xm[oidx + 4] = v1;
    *(unsigned*)&m1out[oidx] = mo;
    *(unsigned*)&m1out[oidx + 4] = mo2;
}

// ---------------- K3: channel-sum of mask1 (2-way split + LDS combine) ----------------
__global__ __launch_bounds__(256) void k_rowsum(const unsigned char* __restrict__ m1,
                                                float* __restrict__ S)
{
    __shared__ float red[128];
    int bi = blockIdx.x;                // b*128 + i
    int b = bi >> 7, i = bi & 127;
    int t = threadIdx.x;
    int j = t & 127, half = t >> 7;
    float s = 0.f;
    size_t base = (size_t)b*C_*HW + (size_t)(half*96)*HW + (size_t)i*H_ + j;
    for (int c = 0; c < 96; ++c) s += (float)m1[base + (size_t)c*HW];
    if (half) red[j] = s;
    __syncthreads();
    if (!half) S[bi*H_ + j] = s + red[j];
}

// ---------------- K4: window-sum -> expand factor & mh ----------------
__global__ __launch_bounds__(256) void k_facm(const float* __restrict__ S,
                                              float* __restrict__ fac, float* __restrict__ mh)
{
    int px = blockIdx.x*256 + threadIdx.x;
    if (px >= NPIX) return;
    int j = px & 127, i = (px >> 7) & 127, b = px >> 14;
    float w3 = 0.f;
    #pragma unroll
    for (int di = -1; di <= 1; ++di) {
        int gi = i + di; if ((unsigned)gi >= (unsigned)H_) continue;
        #pragma unroll
        for (int dj = -1; dj <= 1; ++dj) {
            int gj = j + dj; if ((unsigned)gj >= (unsigned)H_) continue;
            w3 += S[(b*H_ + gi)*H_ + gj];
        }
    }
    bool v = w3 > 0.f;
    fac[px] = v ? 1728.f / w3 : 0.f;
    mh[px]  = v ? 1.f : 0.f;
}

// ---------------- K4b: weight convert + permute (K-major, no swizzle) ----------------
// web3: tile = p*54 + sc*9 + r, layout [c8 4][e 384][j 8]:
//   value = we[(p*384+e)*1728 + (sc*32 + c8*8 + j)*9 + r]
// wpb3: chunk = p*6+ec, layout [e8 8][co 192][j 8]:
//   value = wp[co*768 + chunk*64 + e8*8 + j]
// gb  : gamma bf16 [co][c]
__global__ __launch_bounds__(256) void k_wcvt(const float* __restrict__ we,
                                              const float* __restrict__ wp,
                                              const float* __restrict__ gamma,
                                              short* __restrict__ web3,
                                              short* __restrict__ wpb3,
                                              short* __restrict__ gb)
{
    int idx = blockIdx.x*256 + threadIdx.x;
    const int N1 = 108*12288;        // 1,327,104
    const int N2 = 12*12288;         // 147,456
    if (idx < N1) {
        int tile = idx / 12288, rem = idx % 12288;
        int g = rem >> 3, j = rem & 7;
        int c8 = g / 384, e = g % 384;
        int p = tile / 54, sc = (tile % 54) / 9, r = tile % 9;
        web3[idx] = (short)f2bf(we[(size_t)(p*384 + e)*1728 + (sc*32 + c8*8 + j)*9 + r]);
    } else if (idx < N1 + N2) {
        int i2 = idx - N1;
        int chunk = i2 / 12288, rem = i2 % 12288;
        int g = rem >> 3, j = rem & 7;
        int e8 = g / 192, co = g % 192;
        wpb3[i2] = (short)f2bf(wp[(size_t)co*E_ + chunk*64 + e8*8 + j]);
    } else {
        int i3 = idx - N1 - N2;
        if (i3 < C_*C_) gb[i3] = (short)f2bf(gamma[i3]);
    }
}

// ---------------- K4c: xm f32 [c][pix] -> xmT bf16 [b][130][130][192] (interior) ----------------
__global__ __launch_bounds__(256) void k_xmt(const float* __restrict__ xm,
                                             short* __restrict__ xmT)
{
    __shared__ float sm[64*65];
    const int gx = blockIdx.x;           // 3072 = 3 cb * 1024 pb
    const int cb = gx >> 10, pb = gx & 1023;
    const int c0 = cb*64, pix0 = pb*64;
    const int b = pix0 >> 14, pixb = pix0 & 16383;
    const int t = threadIdx.x;
    const int lane6 = t & 63, hi4 = t >> 6;
    #pragma unroll
    for (int it = 0; it < 16; ++it) {
        int r4 = it*4 + hi4;
        sm[r4*65 + lane6] = xm[((size_t)(b*C_ + c0 + r4))*HW + pixb + lane6];
    }
    __syncthreads();
    #pragma unroll
    for (int it = 0; it < 2; ++it) {
        int q = it*256 + t;
        int pp = q >> 3, c8 = q & 7;
        int p = pixb + pp;
        int i = p >> 7, j = p & 127;
        bf16x8 v;
        #pragma unroll
        for (int jj = 0; jj < 8; ++jj) v[jj] = (short)f2bf(sm[(c8*8+jj)*65 + pp]);
        *(bf16x8*)&xmT[((size_t)(b*XTPL + (i+1)*XTW + (j+1)))*192 + c0 + c8*8] = v;
    }
}

// ---------------- K5: MFMA fused MBConv — K-major LDS, unrolled taps, dbuf apat ----------------
// 512 blocks x 512 thr (8 waves, 2m x 4e). 2 e-passes of 384; per pass 54 taps.
// All MFMA-operand LDS reads: per-thread invariant base + compile-time immediate. No XOR.
__global__ __launch_bounds__(512, 1) void k_mbconv(
    const short* __restrict__ xmT, const short* __restrict__ web3,
    const short* __restrict__ wpb3, const float* __restrict__ be,
    const float* __restrict__ bp, const float* __restrict__ bcast,
    const float* __restrict__ fac, const float* __restrict__ mh,
    const unsigned char* __restrict__ m1, float* __restrict__ xmy)
{
    __shared__ __align__(16) char smem[147456];
    // expand: apat @0 [2][c8 4][pos 180][8] 23,040 | bB @23,040 [3][c8 4][e 384][8] 73,728 (ends 96,768)
    // proj:   wpB @0 [2][e8 8][co 192][8] 49,152 | hB @49,152 [e8 48][px 128][8] 98,304 (ends 147,456)
    // epi:    fbuf @0 [192][132] f32 101,376
    short* apat = (short*)smem;
    short* bB   = (short*)(smem + 23040);
    short* wpB  = (short*)smem;
    short* hB   = (short*)(smem + 49152);
    float* fbuf = (float*)smem;

    // XCD-aware swizzle: 512 blocks = 8 XCDs x 64 contiguous
    const int blk = (blockIdx.x & 7)*64 + (blockIdx.x >> 3);
    const int b = blk >> 7;                       // 4b x 16ti x 8tj
    const int ti = (blk >> 3) & 15, tj = blk & 7;
    const int i0 = ti*8, j0 = tj*16;              // tile = 8 rows x 16 cols
    const int t = threadIdx.x;
    const int w = t >> 6, l = t & 63;
    const int wm2 = w >> 2, we2 = w & 3;
    const int m0 = wm2 * 64;
    const int lo = l & 15, hi = l >> 4;

// A-patch staging: 720 granules = [c8 4][pos 180]; 512 + 192 full-wave gll + 16 scalar tail.
#define ISSUE_A(sc_, buf_) do {                                                 \
    const int c0_ = (sc_)*32;                                                   \
    {   int q_ = t;                                                             \
        int c8_ = q_ / 180, pos_ = q_ - c8_*180;                                \
        int rr_ = pos_/18, cc_ = pos_ - rr_*18;                                 \
        gll16(&xmT[((size_t)(b*XTPL + (i0+rr_)*XTW + (j0+cc_)))*192 + c0_       \
                   + c8_*8], &apat[(buf_)*5760 + q_*8]);                        \
    }                                                                           \
    if (t < 192) {                                                              \
        int q_ = 512 + t;                                                       \
        int c8_ = q_ / 180, pos_ = q_ - c8_*180;                                \
        int rr_ = pos_/18, cc_ = pos_ - rr_*18;                                 \
        gll16(&xmT[((size_t)(b*XTPL + (i0+rr_)*XTW + (j0+cc_)))*192 + c0_       \
                   + c8_*8], &apat[(buf_)*5760 + q_*8]);                        \
    }                                                                           \
    if (t < 16) {                                                               \
        int q_ = 704 + t;                                                       \
        int pos_ = q_ - 540;             /* c8 = 3 */                           \
        int rr_ = pos_/18, cc_ = pos_ - rr_*18;                                 \
        bf16x8 v_ = *(const bf16x8*)&xmT[((size_t)(b*XTPL + (i0+rr_)*XTW        \
                   + (j0+cc_)))*192 + c0_ + 24];                                \
        *(bf16x8*)&apat[(buf_)*5760 + q_*8] = v_;                               \
    }                                                                           \
} while(0)

#define ISSUE_B(tileIdx_, bufIdx_) do {                                         \
    const size_t off_ = (size_t)(tileIdx_) * 12288;                             \
    short* dst_ = &bB[(bufIdx_) * 12288];                                       \
    for (int it_ = 0; it_ < 3; ++it_) {                                         \
        int q_ = it_*512 + t;                                                   \
        gll16(&web3[off_ + q_*8], &dst_[q_*8]);                                 \
    }                                                                           \
} while(0)

#define ISSUE_WP(chunkIdx_, bufIdx_) do {                                       \
    const size_t off_ = (size_t)(chunkIdx_) * 12288;                            \
    short* dst_ = &wpB[(bufIdx_) * 12288];                                      \
    for (int it_ = 0; it_ < 3; ++it_) {                                         \
        int q_ = it_*512 + t;                                                   \
        gll16(&wpb3[off_ + q_*8], &dst_[q_*8]);                                 \
    }                                                                           \
} while(0)

#define WAITBAR(N_) do {                                                        \
    asm volatile("s_waitcnt vmcnt(" #N_ ") lgkmcnt(0)" ::: "memory");           \
    __builtin_amdgcn_s_barrier();                                               \
    __builtin_amdgcn_sched_barrier(0);                                          \
} while(0)

#define LGKMBAR() do {                                                          \
    asm volatile("s_waitcnt lgkmcnt(0)" ::: "memory");                          \
    __builtin_amdgcn_s_barrier();                                               \
    __builtin_amdgcn_sched_barrier(0);                                          \
} while(0)

    float facr[4][4];
    #pragma unroll
    for (int af = 0; af < 4; ++af)
        #pragma unroll
        for (int reg = 0; reg < 4; ++reg) {
            int px = m0 + af*16 + hi*4 + reg;
            facr[af][reg] = fac[b*HW + (i0 + (px >> 4))*128 + j0 + (px & 15)];
        }
    // per-thread invariant LDS bases (short indices)
    int aoffS[4], boffS[6], hbaseS[4], wbaseS[3];
    #pragma unroll
    for (int af = 0; af < 4; ++af) {
        int px = m0 + af*16 + lo;
        aoffS[af] = (hi*180 + (px >> 4)*18 + (px & 15)) * 8;
        hbaseS[af] = (hi*128 + px) * 8;
    }
    #pragma unroll
    for (int nf = 0; nf < 6; ++nf)
        boffS[nf] = (hi*384 + we2*96 + nf*16 + lo) * 8;
    #pragma unroll
    for (int nf = 0; nf < 3; ++nf)
        wbaseS[nf] = (hi*192 + we2*48 + nf*16 + lo) * 8;

    // prologue
    ISSUE_A(0, 0);
    ISSUE_B(0, 0);
    ISSUE_B(1, 1);

    #pragma unroll 1
    for (int p = 0; p < 2; ++p) {
        // ================= expand: 54 taps (6 sc x 9 unrolled) =================
        f32x4 acc[4][6];
        #pragma unroll
        for (int a = 0; a < 4; ++a)
            #pragma unroll
            for (int n = 0; n < 6; ++n) acc[a][n] = (f32x4){0.f,0.f,0.f,0.f};

        #pragma unroll 1
        for (int sc = 0; sc < 6; ++sc) {
            const int abufS = (sc & 1) * 5760;
            const int tbase = p*54 + sc*9;
            #pragma unroll
            for (int r = 0; r < 9; ++r) {
                const int tm = r % 3;                       // compile-time
                const int d2 = (r + 2) % 3;                 // compile-time
                const int rv = (r/3)*18 + (r%3);            // compile-time
                // schedule: uniform single WAITBAR(3); last two taps drain
                if (sc < 5 || r < 7) {
                    WAITBAR(3);
                    if (r == 0 && sc < 5) ISSUE_A(sc + 1, (sc + 1) & 1);
                    ISSUE_B(tbase + r + 2, d2);
                } else if (r == 7) {
                    WAITBAR(3);
                } else {
                    WAITBAR(0);
                }
                const short* bcur = &bB[tm * 12288];
                bf16x8 a[4], bb[6];
                #pragma unroll
                for (int af = 0; af < 4; ++af)
                    a[af] = *(const bf16x8*)&apat[abufS + aoffS[af] + rv*8];
                #pragma unroll
                for (int nf = 0; nf < 6; ++nf)
                    bb[nf] = *(const bf16x8*)&bcur[boffS[nf]];
                __builtin_amdgcn_s_setprio(1);
                #pragma unroll
                for (int af = 0; af < 4; ++af)
                    #pragma unroll
                    for (int nf = 0; nf < 6; ++nf)
                        acc[af][nf] = __builtin_amdgcn_mfma_f32_16x16x32_bf16(
                            a[af], bb[nf], acc[af][nf], 0, 0, 0);
                __builtin_amdgcn_s_setprio(0);
            }
        }

        // ================= silu -> hB =================
        LGKMBAR();                         // tap-53 reads done; apat/bB dead
        ISSUE_WP(p*6, 0);
        #pragma unroll
        for (int nf = 0; nf < 6; ++nf) {
            int e_loc = we2*96 + nf*16 + lo;
            float bev = be[p*384 + e_loc];
            int hb = (e_loc >> 3)*1024 + (e_loc & 7);
            #pragma unroll
            for (int af = 0; af < 4; ++af)
                #pragma unroll
                for (int reg = 0; reg < 4; ++reg) {
                    int px = m0 + af*16 + hi*4 + reg;
                    float fr = facr[af][reg];
                    float v = acc[af][nf][reg]*fr + bev;
                    float hv = (fr > 0.f) ? v / (1.f + __expf(-v)) : 0.f;
                    hB[hb + px*8] = (short)f2bf(hv);
                }
        }

        // ================= proj: 6 chunks of 64 e =================
        f32x4 accy[4][3];
        #pragma unroll
        for (int a = 0; a < 4; ++a)
            #pragma unroll
            for (int n = 0; n < 3; ++n) accy[a][n] = (f32x4){0.f,0.f,0.f,0.f};

        LGKMBAR();                         // silu hB writes visible to all
        #pragma unroll 1
        for (int ec = 0; ec < 6; ++ec) {
            if (ec > 0) LGKMBAR();         // prev-prev wpB buf reads done before restage
            if (ec < 5) {
                ISSUE_WP(p*6 + ec + 1, (ec + 1) & 1);
                asm volatile("s_waitcnt vmcnt(3) lgkmcnt(0)" ::: "memory");
            } else {
                asm volatile("s_waitcnt vmcnt(0) lgkmcnt(0)" ::: "memory");
            }
            __builtin_amdgcn_s_barrier();
            __builtin_amdgcn_sched_barrier(0);
            const short* wcur = &wpB[(ec & 1) * 12288];
            const short* hcur = &hB[ec * 8192];
            #pragma unroll
            for (int ks = 0; ks < 2; ++ks) {
                bf16x8 a[4], bb[3];
                #pragma unroll
                for (int af = 0; af < 4; ++af)
                    a[af] = *(const bf16x8*)&hcur[ks*4096 + hbaseS[af]];
                #pragma unroll
                for (int nf = 0; nf < 3; ++nf)
                    bb[nf] = *(const bf16x8*)&wcur[ks*6144 + wbaseS[nf]];
                __builtin_amdgcn_s_setprio(1);
                #pragma unroll
                for (int af = 0; af < 4; ++af)
                    #pragma unroll
                    for (int nf = 0; nf < 3; ++nf)
                        accy[af][nf] = __builtin_amdgcn_mfma_f32_16x16x32_bf16(
                            a[af], bb[nf], accy[af][nf], 0, 0, 0);
                __builtin_amdgcn_s_setprio(0);
            }
        }

        // ================= per-pass y accumulate (single fbuf phase) =================
        LGKMBAR();                         // proj reads done; hB/wpB dead
        #pragma unroll
        for (int af = 0; af < 4; ++af)
            #pragma unroll
            for (int nf = 0; nf < 3; ++nf) {
                int co = we2*48 + nf*16 + lo;
                int pxl = m0 + af*16 + hi*4;
                *(f32x4*)&fbuf[co*132 + pxl] = accy[af][nf];
            }
        __syncthreads();
        #pragma unroll 1
        for (int it = 0; it < 12; ++it) {
            int q = it*512 + t;              // 6144 = 192co x 32 px-quads
            int co = q >> 5, px4 = (q & 31) << 2;
            int pi = px4 >> 4, pj = px4 & 15;
            size_t gidx = ((size_t)(b*C_ + co))*HW + (size_t)(i0+pi)*128 + j0 + pj;
            f32x4 pv = *(f32x4*)&fbuf[co*132 + px4];
            f32x4 prev = *(const f32x4*)&xmy[gidx];
            f32x4 o;
            if (p == 0) {
                int pixg = b*HW + (i0+pi)*128 + j0 + pj;
                f32x4 mh4 = *(const f32x4*)&mh[pixg];
                unsigned mu4 = *(const unsigned*)&m1[gidx];
                float bpc = bp[co], bcc = bcast[co];
                #pragma unroll
                for (int k = 0; k < 4; ++k)
                    o[k] = pv[k] + bpc + prev[k] + bcc*(mh4[k] - (float)((mu4 >> (8*k)) & 255u));
            } else {
                #pragma unroll
                for (int k = 0; k < 4; ++k) o[k] = prev[k] + pv[k];
            }
            *(f32x4*)&xmy[gidx] = o;
        }
        __syncthreads();
        if (p == 0) { ISSUE_A(0, 0); ISSUE_B(54, 0); ISSUE_B(55, 1); }
    }
#undef ISSUE_A
#undef ISSUE_B
#undef ISSUE_WP
#undef WAITBAR
#undef LGKMBAR
}

// ---------------- K6: MFMA GDN, 2x128 px tiles ----------------
__global__ __launch_bounds__(512, 2) void k_gdn(
    const short* __restrict__ gb, const float* __restrict__ beta,
    const float* __restrict__ mh, float* __restrict__ dout)
{
    __shared__ __align__(16) char smem[101376];
    short* aB = (short*)smem;               // [256][104] 53,248
    short* bG = (short*)(smem + 53248);     // [192][104] 39,936
    float* fbuf = (float*)smem;             // [192][132]
    const float* y = dout + NOUT;

    const int blk = blockIdx.x;             // 256 = 4b * 64 row-pairs
    const int b = blk >> 6;
    const int row0 = (blk & 63) * 2;
    const int t = threadIdx.x;
    const int w = t >> 6, l = t & 63;
    const int wm = w >> 1, we_ = w & 1;
    const int m0 = wm * 64;
    const int lo = l & 15, hi = l >> 4;

    f32x4 acc[4][6];
    #pragma unroll
    for (int a = 0; a < 4; ++a)
        #pragma unroll
        for (int n = 0; n < 6; ++n) acc[a][n] = (f32x4){0.f,0.f,0.f,0.f};

    #pragma unroll 1
    for (int ch = 0; ch < 2; ++ch) {
        __syncthreads();
        #pragma unroll 1
        for (int it = 0; it < 12; ++it) {
            int q = it*512 + t;                 // 6144 = 96c x 64 px-chunks
            int cL = q >> 6, px4 = (q & 63) << 2;
            int c = ch*96 + cL;
            int pi = px4 >> 7, pj = px4 & 127;
            f32x4 yv = *(const f32x4*)&y[((size_t)(b*C_ + c))*HW + (size_t)(row0+pi)*128 + pj];
            #pragma unroll
            for (int k = 0; k < 4; ++k)
                aB[(px4+k)*104 + cL] = (short)f2bf(yv[k]*yv[k]);
        }
        #pragma unroll 1
        for (int it = 0; it < 5; ++it) {
            int q = it*512 + t;
            if (q < 2304) {
                int co = q / 12, e8 = q - co*12;
                *(bf16x8*)&bG[co*104 + e8*8] = *(const bf16x8*)&gb[co*192 + ch*96 + e8*8];
            }
        }
        __syncthreads();
        #pragma unroll
        for (int ks = 0; ks < 3; ++ks) {
            const int koff = ks*32 + hi*8;
            bf16x8 a[4], bb[6];
            #pragma unroll
            for (int af = 0; af < 4; ++af)
                a[af] = *(const bf16x8*)&aB[(m0 + af*16 + lo)*104 + koff];
            #pragma unroll
            for (int nf = 0; nf < 6; ++nf)
                bb[nf] = *(const bf16x8*)&bG[(we_*96 + nf*16 + lo)*104 + koff];
            #pragma unroll
            for (int af = 0; af < 4; ++af)
                #pragma unroll
                for (int nf = 0; nf < 6; ++nf)
                    acc[af][nf] = __builtin_amdgcn_mfma_f32_16x16x32_bf16(
                        a[af], bb[nf], acc[af][nf], 0, 0, 0);
        }
    }

    #pragma unroll 1
    for (int ph = 0; ph < 2; ++ph) {
        __syncthreads();
        if ((wm >> 1) == ph) {
            #pragma unroll
            for (int af = 0; af < 4; ++af)
                #pragma unroll
                for (int nf = 0; nf < 6; ++nf) {
                    int co = we_*96 + nf*16 + lo;
                    int pxl = (wm&1)*64 + af*16 + hi*4;
                    *(f32x4*)&fbuf[co*132 + pxl] = acc[af][nf];
                }
        }
        __syncthreads();
        #pragma unroll 1
        for (int it = 0; it < 12; ++it) {
            int q = it*512 + t;
            int co = q >> 5, px4 = (q & 31) << 2;
            size_t gidx = ((size_t)(b*C_ + co))*HW + (size_t)(row0+ph)*128 + px4;
            int pixg = b*HW + (row0+ph)*128 + px4;
            f32x4 nv = *(f32x4*)&fbuf[co*132 + px4];
            f32x4 yv = *(const f32x4*)&y[gidx];
            f32x4 mh4 = *(const f32x4*)&mh[pixg];
            float bt = beta[co];
            f32x4 o;
            #pragma unroll
            for (int k = 0; k < 4; ++k)
                o[k] = (mh4[k] > 0.f) ? yv[k]*rsqrtf(bt + nv[k]) : 0.f;
            *(f32x4*)&dout[gidx] = o;
            *(f32x4*)&dout[(size_t)NOUT + gidx] = mh4;   // final mask (y read above)
        }
    }
}

extern "C" void kernel_launch(void* const* d_in, const int* in_sizes, int n_in,
                              void* d_out, int out_size, void* d_ws, size_t ws_size,
                              hipStream_t stream)
{
    const float* ll = (const float*)d_in[0];
    const float* b1 = (const float*)d_in[1];
    const float* b2 = (const float*)d_in[2];
    const float* b3 = (const float*)d_in[3];
    const int* llm = (const int*)d_in[4];
    const int* m1i = (const int*)d_in[5];
    const int* m2i = (const int*)d_in[6];
    const int* m3i = (const int*)d_in[7];
    const float* wc    = (const float*)d_in[8];
    const float* bcast = (const float*)d_in[9];
    const float* we    = (const float*)d_in[10];
    const float* be    = (const float*)d_in[11];
    const float* wp    = (const float*)d_in[12];
    const float* bp    = (const float*)d_in[13];
    const float* gamma = (const float*)d_in[14];
    const float* beta  = (const float*)d_in[15];

    char* ws = (char*)d_ws;
    float* S   = (float*)(ws + OFF_S);
    float* fac = (float*)(ws + OFF_FAC);
    float* mh  = (float*)(ws + OFF_MH);
    unsigned char* mu  = (unsigned char*)(ws + OFF_MU);
    unsigned char* m1b = (unsigned char*)(ws + OFF_M1);
    short* web3 = (short*)(ws + OFF_WEB3);
    short* wpb3 = (short*)(ws + OFF_WPB3);
    short* gb   = (short*)(ws + OFF_GB);

    float* outF = (float*)d_out;
    float* pre = outF;              // [0:NOUT] pre -> xmT halo -> final out
    float* xm  = outF + NOUT;       // [NOUT:2NOUT] xm -> y (in-place) -> final mask
    short* xmT = (short*)d_out;

    k_wcvt<<<dim3(5904), dim3(256), 0, stream>>>(we, wp, gamma, web3, wpb3, gb);
    k_idwt<<<dim3(B_*C_), dim3(512), 0, stream>>>(ll, b1, b2, b3, llm, m1i, m2i, m3i, pre, mu);
    k_cast<<<dim3(6144), dim3(256), 0, stream>>>(pre, mu, wc, bcast, xm, m1b);
    k_zhalo<<<dim3(194), dim3(256), 0, stream>>>(xmT);
    k_xmt<<<dim3(3072), dim3(256), 0, stream>>>(xm, xmT);
    k_rowsum<<<dim3(B_*H_), dim3(256), 0, stream>>>(m1b, S);
    k_facm<<<dim3(NPIX/256), dim3(256), 0, stream>>>(S, fac, mh);
    k_mbconv<<<dim3(512), dim3(512), 0, stream>>>(xmT, web3, wpb3, be, bp, bcast, fac, mh, m1b, xm);
    k_gdn<<<dim3(256), dim3(512), 0, stream>>>(gb, beta, mh, outF);
}